// Round 11
// baseline (427.790 us; speedup 1.0000x reference)
//
#include <hip/hip_runtime.h>

typedef __attribute__((ext_vector_type(8))) __bf16 bf16x8;
typedef __attribute__((ext_vector_type(4))) float f32x4;

__device__ __forceinline__ ushort f2bf(float f) {
  union { float f; unsigned u; } x; x.f = f;
  unsigned r = x.u + 0x7FFFu + ((x.u >> 16) & 1u);
  return (ushort)(r >> 16);
}
__device__ __forceinline__ float bf2f(ushort u) {
  union { unsigned u; float f; } x; x.u = ((unsigned)u) << 16;
  return x.f;
}

__device__ __forceinline__ void gload_lds16(const void* g, void* l) {
  __builtin_amdgcn_global_load_lds(
      (const __attribute__((address_space(1))) void*)g,
      (__attribute__((address_space(3))) void*)l, 16, 0, 0);
}

// ---------------- fp32 -> bf16 convert, 3 tensors per launch ----------------
__global__ __launch_bounds__(256) void cvt3(
    const float4* __restrict__ s0, const float4* __restrict__ s1,
    const float4* __restrict__ s2, ushort4* __restrict__ d0,
    ushort4* __restrict__ d1, ushort4* __restrict__ d2, int n4) {
  int i = blockIdx.x * 256 + threadIdx.x;
  if (i >= n4) return;
  const float4* s = blockIdx.y == 0 ? s0 : (blockIdx.y == 1 ? s1 : s2);
  ushort4* d = blockIdx.y == 0 ? d0 : (blockIdx.y == 1 ? d1 : d2);
  float4 v = s[i];
  ushort4 o;
  o.x = f2bf(v.x); o.y = f2bf(v.y); o.z = f2bf(v.z); o.w = f2bf(v.w);
  d[i] = o;
}

// ================= 256x256 8-wave 1-barrier bf16 GEMM (B^T form) =================
// C[m,n] = f((sum_k A[m,k]*B[n,k])*(SCALED?scale:1) + bias), f=exp if EXPOUT
// 512 threads = 8 waves (2m x 4n), per-wave 128x64. BK=64, dbuf 128KiB LDS,
// frag-major chunks (1KB = one wave-frag in lane order; conflict-free
// ds_read_b128, linear gload_lds dest).
// ONE barrier per K-tile; frag-level software pipeline inside the tile:
//   vmcnt(0) [retire my 8 stages; dist = 1 full tile]  | bar
//   stage next tile (8 gloads, buf c^1)
//   rd A0,B0,B1 (16 ds) | lgkm0 | rd A1 -> aA2 (8 ds, completes under MFMAs)
//   32 MFMA (m0-3 x n0-3) | lgkm0 (≈free) | 32 MFMA (m4-7 x n0-3, aA2)
// Correctness: all reads are from buf c; stages write buf c^1; the top barrier
// rendezvous means every wave finished tile tt-1's reads (lgkm-waited) before
// any wave's tile-tt stage writes c^1. vmcnt(0)+barrier publishes stages.
// Epilogue: C staged to LDS (bf16, 32B-slot XOR swizzle), coalesced flush.
// REDUCE: 0 none; 1 col max+sumexp partials; 2 col plain-sum partials.
template<int BIAS_MODE, int SCALED, int REDUCE, int EXPOUT>
__global__ __launch_bounds__(512, 2) void gemm256(
    const ushort* __restrict__ A, const ushort* __restrict__ B,
    ushort* __restrict__ Cv, const float* __restrict__ bias,
    float* __restrict__ red_max, float* __restrict__ red_sum,
    int N, int K, long sA, long sB, long sC, float scale, int gm, int gn)
{
  extern __shared__ ushort lds[];   // 131072 B

  // ---- tile decode: bijective XCD swizzle + banded order ----
  const int nwg = gridDim.x;
  const int wg = blockIdx.x;
  const int cpx = nwg >> 3;
  const int wid_ = (wg & 7) * cpx + (wg >> 3);
  const int tiles = gm * gn;
  const int bz = wid_ / tiles;
  const int t2 = wid_ - bz * tiles;
  const int band = t2 / (gm << 2);
  const int r2 = t2 - band * (gm << 2);
  const int tile_m = (r2 >> 2) * 256;
  const int tile_n = ((band << 2) + (r2 & 3)) * 256;

  const ushort* Ab = A + (size_t)bz * sA;
  const ushort* Bb = B + (size_t)bz * sB;
  const int t = threadIdx.x;
  const int lane = t & 63;
  const int w = t >> 6;
  const int wr = w >> 2;
  const int wc = w & 3;

  f32x4 acc[8][4] = {};
  bf16x8 aA[4][2], aA2[4][2], bB[4][2];

#define LDA(dst, c, q)                                                                \
  _Pragma("unroll") for (int mi = 0; mi < 4; ++mi)                                    \
  _Pragma("unroll") for (int kk = 0; kk < 2; ++kk)                                    \
    dst[mi][kk] = *(const bf16x8*)&lds[(c) * 16384 +                                  \
        ((wr * 8 + (q) * 4 + mi) * 2 + kk) * 512 + lane * 8];

#define LDB(c, h)                                                                     \
  _Pragma("unroll") for (int nf = 0; nf < 2; ++nf)                                    \
  _Pragma("unroll") for (int kk = 0; kk < 2; ++kk)                                    \
    bB[(h) * 2 + nf][kk] = *(const bf16x8*)&lds[32768 + (c) * 16384 +                 \
        ((wc * 4 + (h) * 2 + nf) * 2 + kk) * 512 + lane * 8];

#define STAGE_A(c, k0, q)                                                             \
  _Pragma("unroll") for (int o = 0; o < 2; ++o) {                                     \
    int g = w * 2 + o;                                                                \
    int rowblk = (g >> 3) * 8 + (q) * 4 + ((g >> 1) & 3);                             \
    int kk = g & 1;                                                                   \
    gload_lds16(Ab + (size_t)(tile_m + rowblk * 16 + (lane & 15)) * K +               \
                    (k0) + kk * 32 + (lane >> 4) * 8,                                 \
                &lds[(c) * 16384 + (rowblk * 2 + kk) * 512]);                         \
  }

#define STAGE_B(c, k0, q)                                                             \
  _Pragma("unroll") for (int o = 0; o < 2; ++o) {                                     \
    int g = w * 2 + o;                                                                \
    int rowblk = (g >> 2) * 4 + (q) * 2 + ((g >> 1) & 1);                             \
    int kk = g & 1;                                                                   \
    gload_lds16(Bb + (size_t)(tile_n + rowblk * 16 + (lane & 15)) * K +               \
                    (k0) + kk * 32 + (lane >> 4) * 8,                                 \
                &lds[32768 + (c) * 16384 + (rowblk * 2 + kk) * 512]);                 \
  }

#define MFMA_PH(FR, MB, NB)                                                           \
  _Pragma("unroll") for (int kk = 0; kk < 2; ++kk)                                    \
  _Pragma("unroll") for (int mi = 0; mi < 4; ++mi)                                    \
  _Pragma("unroll") for (int nf = 0; nf < 2; ++nf)                                    \
    acc[(MB) + mi][(NB) + nf] = __builtin_amdgcn_mfma_f32_16x16x32_bf16(              \
        FR[mi][kk], bB[(NB) + nf][kk], acc[(MB) + mi][(NB) + nf], 0, 0, 0);

  // ---- prologue: stage K-tile 0 into buf 0 ----
  STAGE_A(0, 0, 0);
  STAGE_B(0, 0, 0);
  STAGE_B(0, 0, 1);
  STAGE_A(0, 0, 1);

  const int KT = K >> 6;
  for (int tt = 0; tt < KT; ++tt) {
    const int c = tt & 1;
    asm volatile("s_waitcnt vmcnt(0)" ::: "memory");   // my 8 stages (dist = 1 tile)
    __builtin_amdgcn_s_barrier();                      // publish all waves' stages
    if (tt + 1 < KT) {
      const int k0n = (tt + 1) << 6;
      STAGE_A(c ^ 1, k0n, 0);
      STAGE_B(c ^ 1, k0n, 0);
      STAGE_B(c ^ 1, k0n, 1);
      STAGE_A(c ^ 1, k0n, 1);
    }
    LDA(aA, c, 0);
    LDB(c, 0);
    LDB(c, 1);
    asm volatile("s_waitcnt lgkmcnt(0)" ::: "memory");
    __builtin_amdgcn_sched_barrier(0);
    LDA(aA2, c, 1);                                    // completes under MFMA cluster A
    __builtin_amdgcn_sched_barrier(0);
    __builtin_amdgcn_s_setprio(1);
    MFMA_PH(aA, 0, 0);
    MFMA_PH(aA, 0, 2);
    __builtin_amdgcn_s_setprio(0);
    asm volatile("s_waitcnt lgkmcnt(0)" ::: "memory"); // aA2 ready (≈free)
    __builtin_amdgcn_sched_barrier(0);
    __builtin_amdgcn_s_setprio(1);
    MFMA_PH(aA2, 4, 0);
    MFMA_PH(aA2, 4, 2);
    __builtin_amdgcn_s_setprio(0);
  }
#undef MFMA_PH
#undef STAGE_A
#undef STAGE_B
#undef LDA
#undef LDB

  __builtin_amdgcn_s_barrier();   // all waves' reads done before epilogue LDS reuse

  // ---- epilogue: stage C tile into LDS (bf16, XOR-swizzled 32B slots) ----
  float sm2[4] = {0.f, 0.f, 0.f, 0.f};   // REDUCE==2 column sums
  {
    float bcn[4]; int ccl[4];
#pragma unroll
    for (int nf = 0; nf < 4; ++nf) {
      ccl[nf] = wc * 64 + nf * 16 + (lane & 15);
      bcn[nf] = (BIAS_MODE == 1) ? bias[tile_n + ccl[nf]] : 0.f;
    }
    const int g5 = ((lane >> 4) & 3) << 5;
#pragma unroll
    for (int mi = 0; mi < 8; ++mi) {
#pragma unroll
      for (int j = 0; j < 4; ++j) {
        const int row = wr * 128 + mi * 16 + ((lane >> 4) << 2) + j;
        float bcr = (BIAS_MODE == 2) ? bias[tile_m + row] : 0.f;
#pragma unroll
        for (int nf = 0; nf < 4; ++nf) {
          float val = acc[mi][nf][j];
          if (SCALED) val *= scale;
          if (BIAS_MODE == 1) val += bcn[nf];
          else if (BIAS_MODE == 2) val += bcr;
          if (EXPOUT) val = __expf(val);
          if (REDUCE == 2) sm2[nf] += val;
          *(ushort*)((char*)lds + row * 512 + ((ccl[nf] * 2) ^ g5)) = f2bf(val);
        }
      }
    }
  }
  __syncthreads();
  // ---- coalesced flush: 16 passes x 512 threads x 16B ----
#pragma unroll
  for (int p = 0; p < 16; ++p) {
    int off = p * 8192 + t * 16;
    int row = off >> 9;
    int b = off & 511;
    int bs = b ^ (((row >> 2) & 3) << 5);
    float4 d = *(const float4*)((const char*)lds + row * 512 + bs);
    *(float4*)(Cv + (size_t)bz * sC + (size_t)(tile_m + row) * N + tile_n + (b >> 1)) = d;
  }

  if constexpr (REDUCE == 2) {   // plain column-sum partials (expS path)
    __syncthreads();
    float* sb = (float*)lds;     // [2][256]
#pragma unroll
    for (int nf = 0; nf < 4; ++nf) {
      float s1 = sm2[nf] + __shfl_xor(sm2[nf], 16);
      float Ss = s1 + __shfl_xor(s1, 32);
      if ((lane >> 4) == nf)
        sb[wr * 256 + wc * 64 + nf * 16 + (lane & 15)] = Ss;
    }
    __syncthreads();
    if (t < 256) {
      size_t rb = ((size_t)bz * gm + (tile_m >> 8)) * N + tile_n + t;
      red_sum[rb] = sb[t] + sb[256 + t];
    }
  }
  if constexpr (REDUCE == 1) {   // col max+sumexp partials (raw acc; PV path)
    __syncthreads();
    float* mb = (float*)lds;          // [2][256]
    float* sb = (float*)lds + 512;    // [2][256]
#pragma unroll
    for (int nf = 0; nf < 4; ++nf) {
      const int cl = wc * 64 + nf * 16 + (lane & 15);
      float mx = -1e30f;
#pragma unroll
      for (int mi = 0; mi < 8; ++mi)
#pragma unroll
        for (int j = 0; j < 4; ++j) mx = fmaxf(mx, acc[mi][nf][j]);
      float m1 = fmaxf(mx, __shfl_xor(mx, 16));
      float M = fmaxf(m1, __shfl_xor(m1, 32));
      float sm = 0.f;
#pragma unroll
      for (int mi = 0; mi < 8; ++mi)
#pragma unroll
        for (int j = 0; j < 4; ++j) sm += __expf(acc[mi][nf][j] - M);
      float s1 = sm + __shfl_xor(sm, 16);
      float Ss = s1 + __shfl_xor(s1, 32);
      if ((lane >> 4) == nf) {
        mb[wr * 256 + cl] = M;
        sb[wr * 256 + cl] = Ss;
      }
    }
    __syncthreads();
    if (t < 256) {
      float m0 = mb[t], m1v = mb[256 + t];
      float M = fmaxf(m0, m1v);
      float Ss = sb[t] * __expf(m0 - M) + sb[256 + t] * __expf(m1v - M);
      size_t rb = ((size_t)bz * gm + (tile_m >> 8)) * N + tile_n + t;
      red_max[rb] = M;
      red_sum[rb] = Ss;
    }
  }
}

// c[b,k] = 1 / sum_ch red_sum[b][ch][k]. grid: (cols/256, B)
__global__ __launch_bounds__(256) void combine_c(
    const float* __restrict__ red_sum, float* __restrict__ cvec, int cols, int nch)
{
  const int b = blockIdx.y;
  const int c = blockIdx.x * 256 + threadIdx.x;
  float Z = 0.f;
  for (int ch = 0; ch < nch; ++ch)
    Z += red_sum[((size_t)b * nch + ch) * cols + c];
  cvec[(size_t)b * cols + c] = 1.f / Z;
}

// vs[b][d][k] = vpT[b][d][k] * c[b][k]
__global__ __launch_bounds__(256) void scale_v(
    const ushort* __restrict__ vpT, const float* __restrict__ cvec,
    ushort* __restrict__ vs, int S, int DS)
{
  const size_t k8 = ((size_t)blockIdx.x * 256 + threadIdx.x) * 8;
  const int b = (int)(k8 / DS);
  const int kcol = (int)(k8 % S);
  ushort4 u0 = *(const ushort4*)(vpT + k8);
  ushort4 u1 = *(const ushort4*)(vpT + k8 + 4);
  const float* cb = cvec + (size_t)b * S + kcol;
  float4 c0 = *(const float4*)cb;
  float4 c1 = *(const float4*)(cb + 4);
  ushort4 o0, o1;
  o0.x = f2bf(bf2f(u0.x) * c0.x); o0.y = f2bf(bf2f(u0.y) * c0.y);
  o0.z = f2bf(bf2f(u0.z) * c0.z); o0.w = f2bf(bf2f(u0.w) * c0.w);
  o1.x = f2bf(bf2f(u1.x) * c1.x); o1.y = f2bf(bf2f(u1.y) * c1.y);
  o1.z = f2bf(bf2f(u1.z) * c1.z); o1.w = f2bf(bf2f(u1.w) * c1.w);
  *(ushort4*)(vs + k8) = o0;
  *(ushort4*)(vs + k8 + 4) = o1;
}

// combine partials -> M, 1/Z per (b,col). grid: (cols/256, B)
__global__ __launch_bounds__(256) void colsm_combine(
    const float* __restrict__ red_max, const float* __restrict__ red_sum,
    float* __restrict__ Mv, float* __restrict__ Zinv, int cols, int nch)
{
  const int b = blockIdx.y;
  const int c = blockIdx.x * 256 + threadIdx.x;
  float M = -1e30f, Z = 0.f;
  for (int ch = 0; ch < nch; ++ch) {
    size_t o = ((size_t)b * nch + ch) * cols + c;
    float m = red_max[o], s = red_sum[o];
    float nm = fmaxf(M, m);
    Z = Z * __expf(M - nm) + s * __expf(m - nm);
    M = nm;
  }
  Mv[(size_t)b * cols + c] = M;
  Zinv[(size_t)b * cols + c] = 1.f / Z;
}

// final: out1 = softmax(attn over rows), out0 = attn + residual. attn is bf16.
__global__ __launch_bounds__(256) void final_emit(
    const ushort* __restrict__ attnB, const float* __restrict__ q,
    float* __restrict__ out0, float* __restrict__ out1,
    const float* __restrict__ Mv, const float* __restrict__ Zinv,
    int rows, int cols, int rpc)
{
  const int b = blockIdx.y;
  const int ch = blockIdx.z;
  const size_t base = (size_t)b * rows * cols;
  const int c4 = (blockIdx.x * 256 + threadIdx.x) * 4;
  const int r0 = ch * rpc;
  float M[4], Zi[4];
#pragma unroll
  for (int i = 0; i < 4; ++i) {
    M[i] = Mv[(size_t)b * cols + c4 + i];
    Zi[i] = Zinv[(size_t)b * cols + c4 + i];
  }
  for (int r = r0; r < r0 + rpc; ++r) {
    size_t o = base + (size_t)r * cols + c4;
    ushort4 u = *(const ushort4*)(attnB + o);
    float4 qv = *(const float4*)(q + o);
    float a0 = bf2f(u.x), a1 = bf2f(u.y), a2 = bf2f(u.z), a3 = bf2f(u.w);
    float4 wv, s;
    wv.x = __expf(a0 - M[0]) * Zi[0];
    wv.y = __expf(a1 - M[1]) * Zi[1];
    wv.z = __expf(a2 - M[2]) * Zi[2];
    wv.w = __expf(a3 - M[3]) * Zi[3];
    s.x = a0 + qv.x; s.y = a1 + qv.y; s.z = a2 + qv.z; s.w = a3 + qv.w;
    *(float4*)(out1 + o) = wv;
    *(float4*)(out0 + o) = s;
  }
}

extern "C" void kernel_launch(void* const* d_in, const int* in_sizes, int n_in,
                              void* d_out, int out_size, void* d_ws, size_t ws_size,
                              hipStream_t stream) {
  const float* q  = (const float*)d_in[0];
  const float* k  = (const float*)d_in[1];
  const float* v  = (const float*)d_in[2];
  const float* Wq = (const float*)d_in[3];
  const float* bq = (const float*)d_in[4];
  const float* Wk = (const float*)d_in[5];
  const float* bk = (const float*)d_in[6];
  const float* Wv = (const float*)d_in[7];
  const float* bv = (const float*)d_in[8];
  float* out = (float*)d_out;

  const int B = 8, S = 2048, D = 1024;
  const long BS = (long)B * S;
  const long nQKV = BS * D;
  const long nW = (long)D * D;

  // d_out staging: qb/kb/vb bf16 [0,96M) (dead after vpT GEMM);
  // red_s_sum @96M (512KB), c_s @98M (64KB). final_emit overwrites d_out last.
  ushort* qb = (ushort*)d_out;
  ushort* kb = qb + nQKV;
  ushort* vb = kb + nQKV;
  float* red_s_sum = (float*)((char*)d_out + (96ull << 20));
  float* c_s       = (float*)((char*)d_out + (98ull << 20));

  // workspace map:
  //  [0,32M)  qp  -> (dead after scores)  vs
  //  [32,64M) kp  -> (dead after scores)  attnB
  //  [64,96M) vpT -> (dead after scale_v) red_f_max@64M, red_f_sum@65M, Mf@66M, Zf@67M
  //  [96,160M) Wqb/Wkb/Wvb (early) -> expS bf16 [b][q][k]
  char* ws = (char*)d_ws;
  ushort* qp     = (ushort*)ws;
  ushort* kp     = (ushort*)(ws + (32ull << 20));
  ushort* vpT    = (ushort*)(ws + (64ull << 20));
  ushort* Wqb    = (ushort*)(ws + (96ull << 20));
  ushort* Wkb    = Wqb + nW;
  ushort* Wvb    = Wkb + nW;
  ushort* expS   = (ushort*)(ws + (96ull << 20));
  ushort* vs     = (ushort*)ws;
  ushort* attnB  = (ushort*)(ws + (32ull << 20));
  float* red_f_max = (float*)(ws + (64ull << 20));
  float* red_f_sum = (float*)(ws + (65ull << 20));
  float* Mf        = (float*)(ws + (66ull << 20));
  float* Zf        = (float*)(ws + (67ull << 20));

  const int SH = 131072;
  (void)hipFuncSetAttribute(reinterpret_cast<const void*>(&gemm256<1,0,0,0>),
                            hipFuncAttributeMaxDynamicSharedMemorySize, SH);
  (void)hipFuncSetAttribute(reinterpret_cast<const void*>(&gemm256<2,0,0,0>),
                            hipFuncAttributeMaxDynamicSharedMemorySize, SH);
  (void)hipFuncSetAttribute(reinterpret_cast<const void*>(&gemm256<0,1,2,1>),
                            hipFuncAttributeMaxDynamicSharedMemorySize, SH);
  (void)hipFuncSetAttribute(reinterpret_cast<const void*>(&gemm256<0,0,1,0>),
                            hipFuncAttributeMaxDynamicSharedMemorySize, SH);

  // ---- conversions: 2 launches (weights; q/k/v) ----
  {
    int n4w = (int)(nW / 4);
    cvt3<<<dim3((n4w + 255) / 256, 3), 256, 0, stream>>>(
        (const float4*)Wq, (const float4*)Wk, (const float4*)Wv,
        (ushort4*)Wqb, (ushort4*)Wkb, (ushort4*)Wvb, n4w);
    int n4q = (int)(nQKV / 4);
    cvt3<<<dim3((n4q + 255) / 256, 3), 256, 0, stream>>>(
        (const float4*)q, (const float4*)k, (const float4*)v,
        (ushort4*)qb, (ushort4*)kb, (ushort4*)vb, n4q);
  }

  // qp[m][e] = q[m][:]·Wq[e][:] + bq[e]   (gm=64, gn=4)
  gemm256<1,0,0,0><<<dim3(64 * 4), 512, SH, stream>>>(
      qb, Wqb, qp, bq, nullptr, nullptr, D, D, 0, 0, 0, 1.f, 64, 4);
  gemm256<1,0,0,0><<<dim3(64 * 4), 512, SH, stream>>>(
      kb, Wkb, kp, bk, nullptr, nullptr, D, D, 0, 0, 0, 1.f, 64, 4);
  // vpT[b][e][s] = Wv[e][:]·v[b][s][:] + bv[e]   (gm=4, gn=8, batch 8)
  gemm256<2,0,0,0><<<dim3(4 * 8 * B), 512, SH, stream>>>(
      Wvb, vb, vpT, bv, nullptr, nullptr, S, D, 0, (long)S * D, (long)D * S, 1.f, 4, 8);
  // expS = exp(qp·kp^T / 1024) + fused column-sum partials   (gm=8, gn=8, batch 8)
  gemm256<0,1,2,1><<<dim3(8 * 8 * B), 512, SH, stream>>>(
      qp, kp, expS, nullptr, nullptr, red_s_sum,
      S, D, (long)S * D, (long)S * D, (long)S * S, 1.f / 1024.f, 8, 8);

  // c[b,k] = 1/colsum;  vs = vpT * c
  combine_c<<<dim3(S / 256, B), 256, 0, stream>>>(red_s_sum, c_s, S, 8);
  scale_v<<<dim3((int)(nQKV / (256 * 8))), 256, 0, stream>>>(vpT, c_s, vs, S, D * S);

  // attn = expS·vs^T (bf16) + fused final-softmax pass1   (gm=8, gn=4, batch 8)
  gemm256<0,0,1,0><<<dim3(8 * 4 * B), 512, SH, stream>>>(
      expS, vs, attnB, nullptr, red_f_max, red_f_sum,
      D, S, (long)S * S, (long)D * S, (long)S * D, 1.f, 8, 4);

  colsm_combine<<<dim3(D / 256, B), 256, 0, stream>>>(red_f_max, red_f_sum, Mf, Zf, D, 8);
  final_emit<<<dim3(1, B, 128), 256, 0, stream>>>(attnB, q, out, out + nQKV, Mf, Zf, S, D, 16);

  (void)in_sizes; (void)n_in; (void)out_size; (void)ws_size;
}

// Round 12
// 395.821 us; speedup vs baseline: 1.0808x; 1.0808x over previous
//
#include <hip/hip_runtime.h>

typedef __attribute__((ext_vector_type(8))) __bf16 bf16x8;
typedef __attribute__((ext_vector_type(4))) float f32x4;

__device__ __forceinline__ ushort f2bf(float f) {
  union { float f; unsigned u; } x; x.f = f;
  unsigned r = x.u + 0x7FFFu + ((x.u >> 16) & 1u);
  return (ushort)(r >> 16);
}
__device__ __forceinline__ float bf2f(ushort u) {
  union { unsigned u; float f; } x; x.u = ((unsigned)u) << 16;
  return x.f;
}

__device__ __forceinline__ void gload_lds16(const void* g, void* l) {
  __builtin_amdgcn_global_load_lds(
      (const __attribute__((address_space(1))) void*)g,
      (__attribute__((address_space(3))) void*)l, 16, 0, 0);
}

// ---------------- fp32 -> bf16 convert, 3 tensors per launch ----------------
__global__ __launch_bounds__(256) void cvt3(
    const float4* __restrict__ s0, const float4* __restrict__ s1,
    const float4* __restrict__ s2, ushort4* __restrict__ d0,
    ushort4* __restrict__ d1, ushort4* __restrict__ d2, int n4) {
  int i = blockIdx.x * 256 + threadIdx.x;
  if (i >= n4) return;
  const float4* s = blockIdx.y == 0 ? s0 : (blockIdx.y == 1 ? s1 : s2);
  ushort4* d = blockIdx.y == 0 ? d0 : (blockIdx.y == 1 ? d1 : d2);
  float4 v = s[i];
  ushort4 o;
  o.x = f2bf(v.x); o.y = f2bf(v.y); o.z = f2bf(v.z); o.w = f2bf(v.w);
  d[i] = o;
}

// ================= 256x256 8-wave 2-phase bf16 GEMM (B^T form) =================
// Round-10 skeleton (best: 388us) with ONE change: no lgkmcnt(0)/sched_barrier
// pins inside phases — the compiler emits fine-grained counted lgkmcnt between
// each ds_read and its dependent MFMA, interleaving LDS reads with MFMA issue
// (m97/m141 lesson: order-pinning defeats compiler scheduling).
//  phA: WA vmcnt(2) [retire cur A0,B0,B1] | bar | fence | stage A0',B0' |
//       rd A0,B0,B1 (16 ds) interleaved w/ 32 MFMA (m0-3 x n0-3)
//  phB: WB vmcnt(4) [retire cur A1]       | bar | fence | stage B1',A1' |
//       rd A1 (8 ds) interleaved w/ 32 MFMA (m4-7 x n0-3)
// Ledger identical to round 10. Epilogue: LDS-staged coalesced C write.
// REDUCE: 0 none; 1 col max+sumexp partials; 2 col plain-sum partials.
template<int BIAS_MODE, int SCALED, int REDUCE, int EXPOUT>
__global__ __launch_bounds__(512, 2) void gemm256(
    const ushort* __restrict__ A, const ushort* __restrict__ B,
    ushort* __restrict__ Cv, const float* __restrict__ bias,
    float* __restrict__ red_max, float* __restrict__ red_sum,
    int N, int K, long sA, long sB, long sC, float scale, int gm, int gn)
{
  extern __shared__ ushort lds[];   // 131072 B

  // ---- tile decode: bijective XCD swizzle + banded order ----
  const int nwg = gridDim.x;
  const int wg = blockIdx.x;
  const int cpx = nwg >> 3;
  const int wid_ = (wg & 7) * cpx + (wg >> 3);
  const int tiles = gm * gn;
  const int bz = wid_ / tiles;
  const int t2 = wid_ - bz * tiles;
  const int band = t2 / (gm << 2);
  const int r2 = t2 - band * (gm << 2);
  const int tile_m = (r2 >> 2) * 256;
  const int tile_n = ((band << 2) + (r2 & 3)) * 256;

  const ushort* Ab = A + (size_t)bz * sA;
  const ushort* Bb = B + (size_t)bz * sB;
  const int t = threadIdx.x;
  const int lane = t & 63;
  const int w = t >> 6;
  const int wr = w >> 2;
  const int wc = w & 3;

  f32x4 acc[8][4] = {};
  bf16x8 aA[4][2], bB[4][2];

#define LDA(c, q)                                                                     \
  _Pragma("unroll") for (int mi = 0; mi < 4; ++mi)                                    \
  _Pragma("unroll") for (int kk = 0; kk < 2; ++kk)                                    \
    aA[mi][kk] = *(const bf16x8*)&lds[(c) * 16384 +                                   \
        ((wr * 8 + (q) * 4 + mi) * 2 + kk) * 512 + lane * 8];

#define LDB(c, h)                                                                     \
  _Pragma("unroll") for (int nf = 0; nf < 2; ++nf)                                    \
  _Pragma("unroll") for (int kk = 0; kk < 2; ++kk)                                    \
    bB[(h) * 2 + nf][kk] = *(const bf16x8*)&lds[32768 + (c) * 16384 +                 \
        ((wc * 4 + (h) * 2 + nf) * 2 + kk) * 512 + lane * 8];

#define STAGE_A(c, k0, q)                                                             \
  _Pragma("unroll") for (int o = 0; o < 2; ++o) {                                     \
    int g = w * 2 + o;                                                                \
    int rowblk = (g >> 3) * 8 + (q) * 4 + ((g >> 1) & 3);                             \
    int kk = g & 1;                                                                   \
    gload_lds16(Ab + (size_t)(tile_m + rowblk * 16 + (lane & 15)) * K +               \
                    (k0) + kk * 32 + (lane >> 4) * 8,                                 \
                &lds[(c) * 16384 + (rowblk * 2 + kk) * 512]);                         \
  }

#define STAGE_B(c, k0, q)                                                             \
  _Pragma("unroll") for (int o = 0; o < 2; ++o) {                                     \
    int g = w * 2 + o;                                                                \
    int rowblk = (g >> 2) * 4 + (q) * 2 + ((g >> 1) & 1);                             \
    int kk = g & 1;                                                                   \
    gload_lds16(Bb + (size_t)(tile_n + rowblk * 16 + (lane & 15)) * K +               \
                    (k0) + kk * 32 + (lane >> 4) * 8,                                 \
                &lds[32768 + (c) * 16384 + (rowblk * 2 + kk) * 512]);                 \
  }

#define MFMA_PH(MB, NB)                                                               \
  _Pragma("unroll") for (int kk = 0; kk < 2; ++kk)                                    \
  _Pragma("unroll") for (int mi = 0; mi < 4; ++mi)                                    \
  _Pragma("unroll") for (int nf = 0; nf < 2; ++nf)                                    \
    acc[(MB) + mi][(NB) + nf] = __builtin_amdgcn_mfma_f32_16x16x32_bf16(              \
        aA[mi][kk], bB[(NB) + nf][kk], acc[(MB) + mi][(NB) + nf], 0, 0, 0);

#define ITER2(c, DOSTAGE, k0n, WA, WB)                                                \
  {                                                                                   \
    /* ---- phase A: m0-3 x n0-3 ---- */                                              \
    asm volatile(WA ::: "memory");                                                    \
    __builtin_amdgcn_s_barrier();                                                     \
    asm volatile("" ::: "memory");                                                    \
    if (DOSTAGE) { STAGE_A((c) ^ 1, k0n, 0); STAGE_B((c) ^ 1, k0n, 0); }              \
    LDA(c, 0);                                                                        \
    LDB(c, 0);                                                                        \
    LDB(c, 1);                                                                        \
    __builtin_amdgcn_s_setprio(1);                                                    \
    MFMA_PH(0, 0);                                                                    \
    MFMA_PH(0, 2);                                                                    \
    __builtin_amdgcn_s_setprio(0);                                                    \
    /* ---- phase B: m4-7 x n0-3 ---- */                                              \
    asm volatile(WB ::: "memory");                                                    \
    __builtin_amdgcn_s_barrier();                                                     \
    asm volatile("" ::: "memory");                                                    \
    if (DOSTAGE) { STAGE_B((c) ^ 1, k0n, 1); STAGE_A((c) ^ 1, k0n, 1); }              \
    LDA(c, 1);                                                                        \
    __builtin_amdgcn_s_setprio(1);                                                    \
    MFMA_PH(4, 0);                                                                    \
    MFMA_PH(4, 2);                                                                    \
    __builtin_amdgcn_s_setprio(0);                                                    \
  }

  // ---- prologue: stage K-tile 0 into buf 0, issue order A0,B0,B1,A1 ----
  STAGE_A(0, 0, 0);
  STAGE_B(0, 0, 0);
  STAGE_B(0, 0, 1);
  STAGE_A(0, 0, 1);

  const int KT = K >> 6;
  for (int tt = 0; tt < KT - 1; ++tt) {
    const int c = tt & 1;
    const int k0n = (tt + 1) << 6;
    ITER2(c, true, k0n, "s_waitcnt vmcnt(2)", "s_waitcnt vmcnt(4)");
  }
  // peeled last K-tile: no staging
  ITER2(((KT - 1) & 1), false, 0, "s_waitcnt vmcnt(2)", "s_waitcnt vmcnt(0)");

#undef ITER2
#undef MFMA_PH
#undef STAGE_A
#undef STAGE_B
#undef LDA
#undef LDB

  __builtin_amdgcn_s_barrier();   // all MFMA/ds reads done before epilogue LDS reuse

  // ---- epilogue: stage C tile into LDS (bf16, XOR-swizzled 32B slots) ----
  float sm2[4] = {0.f, 0.f, 0.f, 0.f};   // REDUCE==2 column sums
  {
    float bcn[4]; int ccl[4];
#pragma unroll
    for (int nf = 0; nf < 4; ++nf) {
      ccl[nf] = wc * 64 + nf * 16 + (lane & 15);
      bcn[nf] = (BIAS_MODE == 1) ? bias[tile_n + ccl[nf]] : 0.f;
    }
    const int g5 = ((lane >> 4) & 3) << 5;
#pragma unroll
    for (int mi = 0; mi < 8; ++mi) {
#pragma unroll
      for (int j = 0; j < 4; ++j) {
        const int row = wr * 128 + mi * 16 + ((lane >> 4) << 2) + j;
        float bcr = (BIAS_MODE == 2) ? bias[tile_m + row] : 0.f;
#pragma unroll
        for (int nf = 0; nf < 4; ++nf) {
          float val = acc[mi][nf][j];
          if (SCALED) val *= scale;
          if (BIAS_MODE == 1) val += bcn[nf];
          else if (BIAS_MODE == 2) val += bcr;
          if (EXPOUT) val = __expf(val);
          if (REDUCE == 2) sm2[nf] += val;
          *(ushort*)((char*)lds + row * 512 + ((ccl[nf] * 2) ^ g5)) = f2bf(val);
        }
      }
    }
  }
  __syncthreads();
  // ---- coalesced flush: 16 passes x 512 threads x 16B ----
#pragma unroll
  for (int p = 0; p < 16; ++p) {
    int off = p * 8192 + t * 16;
    int row = off >> 9;
    int b = off & 511;
    int bs = b ^ (((row >> 2) & 3) << 5);
    float4 d = *(const float4*)((const char*)lds + row * 512 + bs);
    *(float4*)(Cv + (size_t)bz * sC + (size_t)(tile_m + row) * N + tile_n + (b >> 1)) = d;
  }

  if constexpr (REDUCE == 2) {   // plain column-sum partials (expS path)
    __syncthreads();
    float* sb = (float*)lds;     // [2][256]
#pragma unroll
    for (int nf = 0; nf < 4; ++nf) {
      float s1 = sm2[nf] + __shfl_xor(sm2[nf], 16);
      float Ss = s1 + __shfl_xor(s1, 32);
      if ((lane >> 4) == nf)
        sb[wr * 256 + wc * 64 + nf * 16 + (lane & 15)] = Ss;
    }
    __syncthreads();
    if (t < 256) {
      size_t rb = ((size_t)bz * gm + (tile_m >> 8)) * N + tile_n + t;
      red_sum[rb] = sb[t] + sb[256 + t];
    }
  }
  if constexpr (REDUCE == 1) {   // col max+sumexp partials (raw acc; PV path)
    __syncthreads();
    float* mb = (float*)lds;          // [2][256]
    float* sb = (float*)lds + 512;    // [2][256]
#pragma unroll
    for (int nf = 0; nf < 4; ++nf) {
      const int cl = wc * 64 + nf * 16 + (lane & 15);
      float mx = -1e30f;
#pragma unroll
      for (int mi = 0; mi < 8; ++mi)
#pragma unroll
        for (int j = 0; j < 4; ++j) mx = fmaxf(mx, acc[mi][nf][j]);
      float m1 = fmaxf(mx, __shfl_xor(mx, 16));
      float M = fmaxf(m1, __shfl_xor(m1, 32));
      float sm = 0.f;
#pragma unroll
      for (int mi = 0; mi < 8; ++mi)
#pragma unroll
        for (int j = 0; j < 4; ++j) sm += __expf(acc[mi][nf][j] - M);
      float s1 = sm + __shfl_xor(sm, 16);
      float Ss = s1 + __shfl_xor(s1, 32);
      if ((lane >> 4) == nf) {
        mb[wr * 256 + cl] = M;
        sb[wr * 256 + cl] = Ss;
      }
    }
    __syncthreads();
    if (t < 256) {
      float m0 = mb[t], m1v = mb[256 + t];
      float M = fmaxf(m0, m1v);
      float Ss = sb[t] * __expf(m0 - M) + sb[256 + t] * __expf(m1v - M);
      size_t rb = ((size_t)bz * gm + (tile_m >> 8)) * N + tile_n + t;
      red_max[rb] = M;
      red_sum[rb] = Ss;
    }
  }
}

// c[b,k] = 1 / sum_ch red_sum[b][ch][k]. grid: (cols/256, B)
__global__ __launch_bounds__(256) void combine_c(
    const float* __restrict__ red_sum, float* __restrict__ cvec, int cols, int nch)
{
  const int b = blockIdx.y;
  const int c = blockIdx.x * 256 + threadIdx.x;
  float Z = 0.f;
  for (int ch = 0; ch < nch; ++ch)
    Z += red_sum[((size_t)b * nch + ch) * cols + c];
  cvec[(size_t)b * cols + c] = 1.f / Z;
}

// vs[b][d][k] = vpT[b][d][k] * c[b][k]
__global__ __launch_bounds__(256) void scale_v(
    const ushort* __restrict__ vpT, const float* __restrict__ cvec,
    ushort* __restrict__ vs, int S, int DS)
{
  const size_t k8 = ((size_t)blockIdx.x * 256 + threadIdx.x) * 8;
  const int b = (int)(k8 / DS);
  const int kcol = (int)(k8 % S);
  ushort4 u0 = *(const ushort4*)(vpT + k8);
  ushort4 u1 = *(const ushort4*)(vpT + k8 + 4);
  const float* cb = cvec + (size_t)b * S + kcol;
  float4 c0 = *(const float4*)cb;
  float4 c1 = *(const float4*)(cb + 4);
  ushort4 o0, o1;
  o0.x = f2bf(bf2f(u0.x) * c0.x); o0.y = f2bf(bf2f(u0.y) * c0.y);
  o0.z = f2bf(bf2f(u0.z) * c0.z); o0.w = f2bf(bf2f(u0.w) * c0.w);
  o1.x = f2bf(bf2f(u1.x) * c1.x); o1.y = f2bf(bf2f(u1.y) * c1.y);
  o1.z = f2bf(bf2f(u1.z) * c1.z); o1.w = f2bf(bf2f(u1.w) * c1.w);
  *(ushort4*)(vs + k8) = o0;
  *(ushort4*)(vs + k8 + 4) = o1;
}

// combine partials -> M, 1/Z per (b,col). grid: (cols/256, B)
__global__ __launch_bounds__(256) void colsm_combine(
    const float* __restrict__ red_max, const float* __restrict__ red_sum,
    float* __restrict__ Mv, float* __restrict__ Zinv, int cols, int nch)
{
  const int b = blockIdx.y;
  const int c = blockIdx.x * 256 + threadIdx.x;
  float M = -1e30f, Z = 0.f;
  for (int ch = 0; ch < nch; ++ch) {
    size_t o = ((size_t)b * nch + ch) * cols + c;
    float m = red_max[o], s = red_sum[o];
    float nm = fmaxf(M, m);
    Z = Z * __expf(M - nm) + s * __expf(m - nm);
    M = nm;
  }
  Mv[(size_t)b * cols + c] = M;
  Zinv[(size_t)b * cols + c] = 1.f / Z;
}

// final: out1 = softmax(attn over rows), out0 = attn + residual. attn is bf16.
__global__ __launch_bounds__(256) void final_emit(
    const ushort* __restrict__ attnB, const float* __restrict__ q,
    float* __restrict__ out0, float* __restrict__ out1,
    const float* __restrict__ Mv, const float* __restrict__ Zinv,
    int rows, int cols, int rpc)
{
  const int b = blockIdx.y;
  const int ch = blockIdx.z;
  const size_t base = (size_t)b * rows * cols;
  const int c4 = (blockIdx.x * 256 + threadIdx.x) * 4;
  const int r0 = ch * rpc;
  float M[4], Zi[4];
#pragma unroll
  for (int i = 0; i < 4; ++i) {
    M[i] = Mv[(size_t)b * cols + c4 + i];
    Zi[i] = Zinv[(size_t)b * cols + c4 + i];
  }
  for (int r = r0; r < r0 + rpc; ++r) {
    size_t o = base + (size_t)r * cols + c4;
    ushort4 u = *(const ushort4*)(attnB + o);
    float4 qv = *(const float4*)(q + o);
    float a0 = bf2f(u.x), a1 = bf2f(u.y), a2 = bf2f(u.z), a3 = bf2f(u.w);
    float4 wv, s;
    wv.x = __expf(a0 - M[0]) * Zi[0];
    wv.y = __expf(a1 - M[1]) * Zi[1];
    wv.z = __expf(a2 - M[2]) * Zi[2];
    wv.w = __expf(a3 - M[3]) * Zi[3];
    s.x = a0 + qv.x; s.y = a1 + qv.y; s.z = a2 + qv.z; s.w = a3 + qv.w;
    *(float4*)(out1 + o) = wv;
    *(float4*)(out0 + o) = s;
  }
}

extern "C" void kernel_launch(void* const* d_in, const int* in_sizes, int n_in,
                              void* d_out, int out_size, void* d_ws, size_t ws_size,
                              hipStream_t stream) {
  const float* q  = (const float*)d_in[0];
  const float* k  = (const float*)d_in[1];
  const float* v  = (const float*)d_in[2];
  const float* Wq = (const float*)d_in[3];
  const float* bq = (const float*)d_in[4];
  const float* Wk = (const float*)d_in[5];
  const float* bk = (const float*)d_in[6];
  const float* Wv = (const float*)d_in[7];
  const float* bv = (const float*)d_in[8];
  float* out = (float*)d_out;

  const int B = 8, S = 2048, D = 1024;
  const long BS = (long)B * S;
  const long nQKV = BS * D;
  const long nW = (long)D * D;

  // d_out staging: qb/kb/vb bf16 [0,96M) (dead after vpT GEMM);
  // red_s_sum @96M (512KB), c_s @98M (64KB). final_emit overwrites d_out last.
  ushort* qb = (ushort*)d_out;
  ushort* kb = qb + nQKV;
  ushort* vb = kb + nQKV;
  float* red_s_sum = (float*)((char*)d_out + (96ull << 20));
  float* c_s       = (float*)((char*)d_out + (98ull << 20));

  // workspace map:
  //  [0,32M)  qp  -> (dead after scores)  vs
  //  [32,64M) kp  -> (dead after scores)  attnB
  //  [64,96M) vpT -> (dead after scale_v) red_f_max@64M, red_f_sum@65M, Mf@66M, Zf@67M
  //  [96,160M) Wqb/Wkb/Wvb (early) -> expS bf16 [b][q][k]
  char* ws = (char*)d_ws;
  ushort* qp     = (ushort*)ws;
  ushort* kp     = (ushort*)(ws + (32ull << 20));
  ushort* vpT    = (ushort*)(ws + (64ull << 20));
  ushort* Wqb    = (ushort*)(ws + (96ull << 20));
  ushort* Wkb    = Wqb + nW;
  ushort* Wvb    = Wkb + nW;
  ushort* expS   = (ushort*)(ws + (96ull << 20));
  ushort* vs     = (ushort*)ws;
  ushort* attnB  = (ushort*)(ws + (32ull << 20));
  float* red_f_max = (float*)(ws + (64ull << 20));
  float* red_f_sum = (float*)(ws + (65ull << 20));
  float* Mf        = (float*)(ws + (66ull << 20));
  float* Zf        = (float*)(ws + (67ull << 20));

  const int SH = 131072;
  (void)hipFuncSetAttribute(reinterpret_cast<const void*>(&gemm256<1,0,0,0>),
                            hipFuncAttributeMaxDynamicSharedMemorySize, SH);
  (void)hipFuncSetAttribute(reinterpret_cast<const void*>(&gemm256<2,0,0,0>),
                            hipFuncAttributeMaxDynamicSharedMemorySize, SH);
  (void)hipFuncSetAttribute(reinterpret_cast<const void*>(&gemm256<0,1,2,1>),
                            hipFuncAttributeMaxDynamicSharedMemorySize, SH);
  (void)hipFuncSetAttribute(reinterpret_cast<const void*>(&gemm256<0,0,1,0>),
                            hipFuncAttributeMaxDynamicSharedMemorySize, SH);

  // ---- conversions: 2 launches (weights; q/k/v) ----
  {
    int n4w = (int)(nW / 4);
    cvt3<<<dim3((n4w + 255) / 256, 3), 256, 0, stream>>>(
        (const float4*)Wq, (const float4*)Wk, (const float4*)Wv,
        (ushort4*)Wqb, (ushort4*)Wkb, (ushort4*)Wvb, n4w);
    int n4q = (int)(nQKV / 4);
    cvt3<<<dim3((n4q + 255) / 256, 3), 256, 0, stream>>>(
        (const float4*)q, (const float4*)k, (const float4*)v,
        (ushort4*)qb, (ushort4*)kb, (ushort4*)vb, n4q);
  }

  // qp[m][e] = q[m][:]·Wq[e][:] + bq[e]   (gm=64, gn=4)
  gemm256<1,0,0,0><<<dim3(64 * 4), 512, SH, stream>>>(
      qb, Wqb, qp, bq, nullptr, nullptr, D, D, 0, 0, 0, 1.f, 64, 4);
  gemm256<1,0,0,0><<<dim3(64 * 4), 512, SH, stream>>>(
      kb, Wkb, kp, bk, nullptr, nullptr, D, D, 0, 0, 0, 1.f, 64, 4);
  // vpT[b][e][s] = Wv[e][:]·v[b][s][:] + bv[e]   (gm=4, gn=8, batch 8)
  gemm256<2,0,0,0><<<dim3(4 * 8 * B), 512, SH, stream>>>(
      Wvb, vb, vpT, bv, nullptr, nullptr, S, D, 0, (long)S * D, (long)D * S, 1.f, 4, 8);
  // expS = exp(qp·kp^T / 1024) + fused column-sum partials   (gm=8, gn=8, batch 8)
  gemm256<0,1,2,1><<<dim3(8 * 8 * B), 512, SH, stream>>>(
      qp, kp, expS, nullptr, nullptr, red_s_sum,
      S, D, (long)S * D, (long)S * D, (long)S * S, 1.f / 1024.f, 8, 8);

  // c[b,k] = 1/colsum;  vs = vpT * c
  combine_c<<<dim3(S / 256, B), 256, 0, stream>>>(red_s_sum, c_s, S, 8);
  scale_v<<<dim3((int)(nQKV / (256 * 8))), 256, 0, stream>>>(vpT, c_s, vs, S, D * S);

  // attn = expS·vs^T (bf16) + fused final-softmax pass1   (gm=8, gn=4, batch 8)
  gemm256<0,0,1,0><<<dim3(8 * 4 * B), 512, SH, stream>>>(
      expS, vs, attnB, nullptr, red_f_max, red_f_sum,
      D, S, (long)S * S, (long)D * S, (long)S * D, 1.f, 8, 4);

  colsm_combine<<<dim3(D / 256, B), 256, 0, stream>>>(red_f_max, red_f_sum, Mf, Zf, D, 8);
  final_emit<<<dim3(1, B, 128), 256, 0, stream>>>(attnB, q, out, out + nQKV, Mf, Zf, S, D, 16);

  (void)in_sizes; (void)n_in; (void)out_size; (void)ws_size;
}

// Round 13
// 393.533 us; speedup vs baseline: 1.0870x; 1.0058x over previous
//
#include <hip/hip_runtime.h>

typedef __attribute__((ext_vector_type(8))) __bf16 bf16x8;
typedef __attribute__((ext_vector_type(4))) float f32x4;

__device__ __forceinline__ ushort f2bf(float f) {
  union { float f; unsigned u; } x; x.f = f;
  unsigned r = x.u + 0x7FFFu + ((x.u >> 16) & 1u);
  return (ushort)(r >> 16);
}
__device__ __forceinline__ float bf2f(ushort u) {
  union { unsigned u; float f; } x; x.u = ((unsigned)u) << 16;
  return x.f;
}

__device__ __forceinline__ void gload_lds16(const void* g, void* l) {
  __builtin_amdgcn_global_load_lds(
      (const __attribute__((address_space(1))) void*)g,
      (__attribute__((address_space(3))) void*)l, 16, 0, 0);
}

// ---------------- fp32 -> bf16 convert, 3 tensors per launch ----------------
__global__ __launch_bounds__(256) void cvt3(
    const float4* __restrict__ s0, const float4* __restrict__ s1,
    const float4* __restrict__ s2, ushort4* __restrict__ d0,
    ushort4* __restrict__ d1, ushort4* __restrict__ d2, int n4) {
  int i = blockIdx.x * 256 + threadIdx.x;
  if (i >= n4) return;
  const float4* s = blockIdx.y == 0 ? s0 : (blockIdx.y == 1 ? s1 : s2);
  ushort4* d = blockIdx.y == 0 ? d0 : (blockIdx.y == 1 ? d1 : d2);
  float4 v = s[i];
  ushort4 o;
  o.x = f2bf(v.x); o.y = f2bf(v.y); o.z = f2bf(v.z); o.w = f2bf(v.w);
  d[i] = o;
}

// ============ 256x256 8-wave 8-phase bf16 GEMM (m201-pattern, B^T form) ============
// C[m,n] = f((sum_k A[m,k]*B[n,k])*(SCALED?scale:1) + bias), f=exp if EXPOUT
// 512 thr = 8 waves (2m x 4n), per-wave 128x64. BK=64, even tiles->buf0, odd->buf1.
// Frag-major LDS chunks (1KB = one wave-frag in lane order; conflict-free
// ds_read_b128; linear gload_lds dest). 128KiB LDS.
// 8 phases per 2-K-tile iter; per phase: {vmcnt(8) | ds_reads | stage 1 half |
// bar | lgkm0 | 16 MFMA | bar}. Uniform FIFO orbit: 5 halves in flight; a half
// staged at phase p is retired by ALL waves at p+5 (their vmcnt(8)) and first
// read at p+6 — retirement happens-before a barrier happens-before the read.
// Stage slots: p1:SA1(odd tile, read p7 same iter), p2..p5: SA0/SB0/SB1/SA1 of
// tile t+2 (buf0), p6..p8: SA0/SB0/SB1 of tile t+3 (buf1). All stages >=1 bar
// after that chunk's last read (WAR safe). Last iter: waits 8,8,6,4,2,0,-,-.
// Reads per phase: p1:A0,B0(b0) p2:B1(b0) p3:A1(b0) p4:- p5:A0,B0(b1) p6:B1(b1)
// p7:A1(b1) p8:-  (MFMA quadrants m0-3/m4-7 x n0-1/n2-3 per tile).
// Epilogue: C staged to LDS (XOR-swizzled 32B slots), coalesced flush.
// REDUCE: 0 none; 1 col max+sumexp partials; 2 col plain-sum partials.
template<int BIAS_MODE, int SCALED, int REDUCE, int EXPOUT>
__global__ __launch_bounds__(512, 2) void gemm256(
    const ushort* __restrict__ A, const ushort* __restrict__ B,
    ushort* __restrict__ Cv, const float* __restrict__ bias,
    float* __restrict__ red_max, float* __restrict__ red_sum,
    int N, int K, long sA, long sB, long sC, float scale, int gm, int gn)
{
  extern __shared__ ushort lds[];   // 131072 B

  // ---- tile decode: bijective XCD swizzle + banded order ----
  const int nwg = gridDim.x;
  const int wg = blockIdx.x;
  const int cpx = nwg >> 3;
  const int wid_ = (wg & 7) * cpx + (wg >> 3);
  const int tiles = gm * gn;
  const int bz = wid_ / tiles;
  const int t2 = wid_ - bz * tiles;
  const int band = t2 / (gm << 2);
  const int r2 = t2 - band * (gm << 2);
  const int tile_m = (r2 >> 2) * 256;
  const int tile_n = ((band << 2) + (r2 & 3)) * 256;

  const ushort* Ab = A + (size_t)bz * sA;
  const ushort* Bb = B + (size_t)bz * sB;
  const int t = threadIdx.x;
  const int lane = t & 63;
  const int w = t >> 6;
  const int wr = w >> 2;
  const int wc = w & 3;

  f32x4 acc[8][4] = {};
  bf16x8 aA[4][2], bB[4][2];

#define LDA(c, q)                                                                     \
  _Pragma("unroll") for (int mi = 0; mi < 4; ++mi)                                    \
  _Pragma("unroll") for (int kk = 0; kk < 2; ++kk)                                    \
    aA[mi][kk] = *(const bf16x8*)&lds[(c) * 16384 +                                   \
        ((wr * 8 + (q) * 4 + mi) * 2 + kk) * 512 + lane * 8];

#define LDB(c, h)                                                                     \
  _Pragma("unroll") for (int nf = 0; nf < 2; ++nf)                                    \
  _Pragma("unroll") for (int kk = 0; kk < 2; ++kk)                                    \
    bB[(h) * 2 + nf][kk] = *(const bf16x8*)&lds[32768 + (c) * 16384 +                 \
        ((wc * 4 + (h) * 2 + nf) * 2 + kk) * 512 + lane * 8];

#define STAGE_A(c, k0, q)                                                             \
  _Pragma("unroll") for (int o = 0; o < 2; ++o) {                                     \
    int g = w * 2 + o;                                                                \
    int rowblk = (g >> 3) * 8 + (q) * 4 + ((g >> 1) & 3);                             \
    int kk = g & 1;                                                                   \
    gload_lds16(Ab + (size_t)(tile_m + rowblk * 16 + (lane & 15)) * K +               \
                    (k0) + kk * 32 + (lane >> 4) * 8,                                 \
                &lds[(c) * 16384 + (rowblk * 2 + kk) * 512]);                         \
  }

#define STAGE_B(c, k0, q)                                                             \
  _Pragma("unroll") for (int o = 0; o < 2; ++o) {                                     \
    int g = w * 2 + o;                                                                \
    int rowblk = (g >> 2) * 4 + (q) * 2 + ((g >> 1) & 1);                             \
    int kk = g & 1;                                                                   \
    gload_lds16(Bb + (size_t)(tile_n + rowblk * 16 + (lane & 15)) * K +               \
                    (k0) + kk * 32 + (lane >> 4) * 8,                                 \
                &lds[32768 + (c) * 16384 + (rowblk * 2 + kk) * 512]);                 \
  }

#define MFMA_PH(MB, NB)                                                               \
  _Pragma("unroll") for (int kk = 0; kk < 2; ++kk)                                    \
  _Pragma("unroll") for (int mi = 0; mi < 4; ++mi)                                    \
  _Pragma("unroll") for (int nf = 0; nf < 2; ++nf)                                    \
    acc[(MB) + mi][(NB) + nf] = __builtin_amdgcn_mfma_f32_16x16x32_bf16(              \
        aA[mi][kk], bB[(NB) + nf][kk], acc[(MB) + mi][(NB) + nf], 0, 0, 0);

#define BARR __builtin_amdgcn_s_barrier()
#define LGKM0 do { asm volatile("s_waitcnt lgkmcnt(0)" ::: "memory");                 \
                   __builtin_amdgcn_sched_barrier(0); } while (0)

#define ITER8(kA1, k2, k3, ST, W1, W2, W3, W4, W5, W6, W7, W8)                        \
  {                                                                                   \
    /* p1: tile t quad (m0-3,n0-1) */                                                 \
    asm volatile(W1 ::: "memory");                                                    \
    LDA(0, 0); LDB(0, 0);                                                             \
    STAGE_A(1, kA1, 1);                                                               \
    BARR; LGKM0;                                                                      \
    __builtin_amdgcn_s_setprio(1); MFMA_PH(0, 0); __builtin_amdgcn_s_setprio(0);      \
    BARR;                                                                             \
    /* p2: (m0-3,n2-3) */                                                             \
    asm volatile(W2 ::: "memory");                                                    \
    LDB(0, 1);                                                                        \
    if (ST) STAGE_A(0, k2, 0);                                                        \
    BARR; LGKM0;                                                                      \
    __builtin_amdgcn_s_setprio(1); MFMA_PH(0, 2); __builtin_amdgcn_s_setprio(0);      \
    BARR;                                                                             \
    /* p3: (m4-7,n0-1) */                                                             \
    asm volatile(W3 ::: "memory");                                                    \
    LDA(0, 1);                                                                        \
    if (ST) STAGE_B(0, k2, 0);                                                        \
    BARR; LGKM0;                                                                      \
    __builtin_amdgcn_s_setprio(1); MFMA_PH(4, 0); __builtin_amdgcn_s_setprio(0);      \
    BARR;                                                                             \
    /* p4: (m4-7,n2-3) */                                                             \
    asm volatile(W4 ::: "memory");                                                    \
    if (ST) STAGE_B(0, k2, 1);                                                        \
    BARR;                                                                             \
    __builtin_amdgcn_s_setprio(1); MFMA_PH(4, 2); __builtin_amdgcn_s_setprio(0);      \
    BARR;                                                                             \
    /* p5: tile t+1 quad (m0-3,n0-1) */                                               \
    asm volatile(W5 ::: "memory");                                                    \
    LDA(1, 0); LDB(1, 0);                                                             \
    if (ST) STAGE_A(0, k2, 1);                                                        \
    BARR; LGKM0;                                                                      \
    __builtin_amdgcn_s_setprio(1); MFMA_PH(0, 0); __builtin_amdgcn_s_setprio(0);      \
    BARR;                                                                             \
    /* p6: (m0-3,n2-3) */                                                             \
    asm volatile(W6 ::: "memory");                                                    \
    LDB(1, 1);                                                                        \
    if (ST) STAGE_A(1, k3, 0);                                                        \
    BARR; LGKM0;                                                                      \
    __builtin_amdgcn_s_setprio(1); MFMA_PH(0, 2); __builtin_amdgcn_s_setprio(0);      \
    BARR;                                                                             \
    /* p7: (m4-7,n0-1) */                                                             \
    asm volatile(W7 ::: "memory");                                                    \
    LDA(1, 1);                                                                        \
    if (ST) STAGE_B(1, k3, 0);                                                        \
    BARR; LGKM0;                                                                      \
    __builtin_amdgcn_s_setprio(1); MFMA_PH(4, 0); __builtin_amdgcn_s_setprio(0);      \
    BARR;                                                                             \
    /* p8: (m4-7,n2-3) */                                                             \
    asm volatile(W8 ::: "memory");                                                    \
    if (ST) STAGE_B(1, k3, 1);                                                        \
    BARR;                                                                             \
    __builtin_amdgcn_s_setprio(1); MFMA_PH(4, 2); __builtin_amdgcn_s_setprio(0);      \
    BARR;                                                                             \
  }

  // ---- prologue: 7 halves in FIFO order SA0(0),SB0(0),SB1(0),SA1(0),SA0(1),
  //      SB0(1),SB1(1); retire first 3 (incl. p1's A0,B0), publish via barrier.
  STAGE_A(0, 0, 0);
  STAGE_B(0, 0, 0);
  STAGE_B(0, 0, 1);
  STAGE_A(0, 0, 1);
  STAGE_A(1, 64, 0);
  STAGE_B(1, 64, 0);
  STAGE_B(1, 64, 1);
  asm volatile("s_waitcnt vmcnt(8)" ::: "memory");
  BARR;

  const int ITERS = K >> 7;   // 2 K-tiles (BK=64) per iter
  for (int it = 0; it < ITERS - 1; ++it) {
    const int kA1 = (2 * it + 1) << 6;
    const int k2  = (2 * it + 2) << 6;
    const int k3  = (2 * it + 3) << 6;
    ITER8(kA1, k2, k3, true,
          "s_waitcnt vmcnt(8)", "s_waitcnt vmcnt(8)", "s_waitcnt vmcnt(8)",
          "s_waitcnt vmcnt(8)", "s_waitcnt vmcnt(8)", "s_waitcnt vmcnt(8)",
          "s_waitcnt vmcnt(8)", "s_waitcnt vmcnt(8)");
  }
  {
    const int kA1 = (K >> 6 << 6) - 64;   // (KT-1)*64
    ITER8(kA1, 0, 0, false,
          "s_waitcnt vmcnt(8)", "s_waitcnt vmcnt(8)", "s_waitcnt vmcnt(6)",
          "s_waitcnt vmcnt(4)", "s_waitcnt vmcnt(2)", "s_waitcnt vmcnt(0)",
          "s_nop 0", "s_nop 0");
  }

#undef ITER8
#undef MFMA_PH
#undef STAGE_A
#undef STAGE_B
#undef LDA
#undef LDB
#undef LGKM0

  BARR;   // all waves' reads done before epilogue LDS reuse
#undef BARR

  // ---- epilogue: stage C tile into LDS (bf16, XOR-swizzled 32B slots) ----
  float sm2[4] = {0.f, 0.f, 0.f, 0.f};   // REDUCE==2 column sums
  {
    float bcn[4]; int ccl[4];
#pragma unroll
    for (int nf = 0; nf < 4; ++nf) {
      ccl[nf] = wc * 64 + nf * 16 + (lane & 15);
      bcn[nf] = (BIAS_MODE == 1) ? bias[tile_n + ccl[nf]] : 0.f;
    }
    const int g5 = ((lane >> 4) & 3) << 5;
#pragma unroll
    for (int mi = 0; mi < 8; ++mi) {
#pragma unroll
      for (int j = 0; j < 4; ++j) {
        const int row = wr * 128 + mi * 16 + ((lane >> 4) << 2) + j;
        float bcr = (BIAS_MODE == 2) ? bias[tile_m + row] : 0.f;
#pragma unroll
        for (int nf = 0; nf < 4; ++nf) {
          float val = acc[mi][nf][j];
          if (SCALED) val *= scale;
          if (BIAS_MODE == 1) val += bcn[nf];
          else if (BIAS_MODE == 2) val += bcr;
          if (EXPOUT) val = __expf(val);
          if (REDUCE == 2) sm2[nf] += val;
          *(ushort*)((char*)lds + row * 512 + ((ccl[nf] * 2) ^ g5)) = f2bf(val);
        }
      }
    }
  }
  __syncthreads();
  // ---- coalesced flush: 16 passes x 512 threads x 16B ----
#pragma unroll
  for (int p = 0; p < 16; ++p) {
    int off = p * 8192 + t * 16;
    int row = off >> 9;
    int b = off & 511;
    int bs = b ^ (((row >> 2) & 3) << 5);
    float4 d = *(const float4*)((const char*)lds + row * 512 + bs);
    *(float4*)(Cv + (size_t)bz * sC + (size_t)(tile_m + row) * N + tile_n + (b >> 1)) = d;
  }

  if constexpr (REDUCE == 2) {   // plain column-sum partials (expS path)
    __syncthreads();
    float* sb = (float*)lds;     // [2][256]
#pragma unroll
    for (int nf = 0; nf < 4; ++nf) {
      float s1 = sm2[nf] + __shfl_xor(sm2[nf], 16);
      float Ss = s1 + __shfl_xor(s1, 32);
      if ((lane >> 4) == nf)
        sb[wr * 256 + wc * 64 + nf * 16 + (lane & 15)] = Ss;
    }
    __syncthreads();
    if (t < 256) {
      size_t rb = ((size_t)bz * gm + (tile_m >> 8)) * N + tile_n + t;
      red_sum[rb] = sb[t] + sb[256 + t];
    }
  }
  if constexpr (REDUCE == 1) {   // col max+sumexp partials (raw acc; PV path)
    __syncthreads();
    float* mb = (float*)lds;          // [2][256]
    float* sb = (float*)lds + 512;    // [2][256]
#pragma unroll
    for (int nf = 0; nf < 4; ++nf) {
      const int cl = wc * 64 + nf * 16 + (lane & 15);
      float mx = -1e30f;
#pragma unroll
      for (int mi = 0; mi < 8; ++mi)
#pragma unroll
        for (int j = 0; j < 4; ++j) mx = fmaxf(mx, acc[mi][nf][j]);
      float m1 = fmaxf(mx, __shfl_xor(mx, 16));
      float M = fmaxf(m1, __shfl_xor(m1, 32));
      float sm = 0.f;
#pragma unroll
      for (int mi = 0; mi < 8; ++mi)
#pragma unroll
        for (int j = 0; j < 4; ++j) sm += __expf(acc[mi][nf][j] - M);
      float s1 = sm + __shfl_xor(sm, 16);
      float Ss = s1 + __shfl_xor(s1, 32);
      if ((lane >> 4) == nf) {
        mb[wr * 256 + cl] = M;
        sb[wr * 256 + cl] = Ss;
      }
    }
    __syncthreads();
    if (t < 256) {
      float m0 = mb[t], m1v = mb[256 + t];
      float M = fmaxf(m0, m1v);
      float Ss = sb[t] * __expf(m0 - M) + sb[256 + t] * __expf(m1v - M);
      size_t rb = ((size_t)bz * gm + (tile_m >> 8)) * N + tile_n + t;
      red_max[rb] = M;
      red_sum[rb] = Ss;
    }
  }
}

// c[b,k] = 1 / sum_ch red_sum[b][ch][k]. grid: (cols/256, B)
__global__ __launch_bounds__(256) void combine_c(
    const float* __restrict__ red_sum, float* __restrict__ cvec, int cols, int nch)
{
  const int b = blockIdx.y;
  const int c = blockIdx.x * 256 + threadIdx.x;
  float Z = 0.f;
  for (int ch = 0; ch < nch; ++ch)
    Z += red_sum[((size_t)b * nch + ch) * cols + c];
  cvec[(size_t)b * cols + c] = 1.f / Z;
}

// vs[b][d][k] = vpT[b][d][k] * c[b][k]
__global__ __launch_bounds__(256) void scale_v(
    const ushort* __restrict__ vpT, const float* __restrict__ cvec,
    ushort* __restrict__ vs, int S, int DS)
{
  const size_t k8 = ((size_t)blockIdx.x * 256 + threadIdx.x) * 8;
  const int b = (int)(k8 / DS);
  const int kcol = (int)(k8 % S);
  ushort4 u0 = *(const ushort4*)(vpT + k8);
  ushort4 u1 = *(const ushort4*)(vpT + k8 + 4);
  const float* cb = cvec + (size_t)b * S + kcol;
  float4 c0 = *(const float4*)cb;
  float4 c1 = *(const float4*)(cb + 4);
  ushort4 o0, o1;
  o0.x = f2bf(bf2f(u0.x) * c0.x); o0.y = f2bf(bf2f(u0.y) * c0.y);
  o0.z = f2bf(bf2f(u0.z) * c0.z); o0.w = f2bf(bf2f(u0.w) * c0.w);
  o1.x = f2bf(bf2f(u1.x) * c1.x); o1.y = f2bf(bf2f(u1.y) * c1.y);
  o1.z = f2bf(bf2f(u1.z) * c1.z); o1.w = f2bf(bf2f(u1.w) * c1.w);
  *(ushort4*)(vs + k8) = o0;
  *(ushort4*)(vs + k8 + 4) = o1;
}

// combine partials -> M, 1/Z per (b,col). grid: (cols/256, B)
__global__ __launch_bounds__(256) void colsm_combine(
    const float* __restrict__ red_max, const float* __restrict__ red_sum,
    float* __restrict__ Mv, float* __restrict__ Zinv, int cols, int nch)
{
  const int b = blockIdx.y;
  const int c = blockIdx.x * 256 + threadIdx.x;
  float M = -1e30f, Z = 0.f;
  for (int ch = 0; ch < nch; ++ch) {
    size_t o = ((size_t)b * nch + ch) * cols + c;
    float m = red_max[o], s = red_sum[o];
    float nm = fmaxf(M, m);
    Z = Z * __expf(M - nm) + s * __expf(m - nm);
    M = nm;
  }
  Mv[(size_t)b * cols + c] = M;
  Zinv[(size_t)b * cols + c] = 1.f / Z;
}

// final: out1 = softmax(attn over rows), out0 = attn + residual. attn is bf16.
__global__ __launch_bounds__(256) void final_emit(
    const ushort* __restrict__ attnB, const float* __restrict__ q,
    float* __restrict__ out0, float* __restrict__ out1,
    const float* __restrict__ Mv, const float* __restrict__ Zinv,
    int rows, int cols, int rpc)
{
  const int b = blockIdx.y;
  const int ch = blockIdx.z;
  const size_t base = (size_t)b * rows * cols;
  const int c4 = (blockIdx.x * 256 + threadIdx.x) * 4;
  const int r0 = ch * rpc;
  float M[4], Zi[4];
#pragma unroll
  for (int i = 0; i < 4; ++i) {
    M[i] = Mv[(size_t)b * cols + c4 + i];
    Zi[i] = Zinv[(size_t)b * cols + c4 + i];
  }
  for (int r = r0; r < r0 + rpc; ++r) {
    size_t o = base + (size_t)r * cols + c4;
    ushort4 u = *(const ushort4*)(attnB + o);
    float4 qv = *(const float4*)(q + o);
    float a0 = bf2f(u.x), a1 = bf2f(u.y), a2 = bf2f(u.z), a3 = bf2f(u.w);
    float4 wv, s;
    wv.x = __expf(a0 - M[0]) * Zi[0];
    wv.y = __expf(a1 - M[1]) * Zi[1];
    wv.z = __expf(a2 - M[2]) * Zi[2];
    wv.w = __expf(a3 - M[3]) * Zi[3];
    s.x = a0 + qv.x; s.y = a1 + qv.y; s.z = a2 + qv.z; s.w = a3 + qv.w;
    *(float4*)(out1 + o) = wv;
    *(float4*)(out0 + o) = s;
  }
}

extern "C" void kernel_launch(void* const* d_in, const int* in_sizes, int n_in,
                              void* d_out, int out_size, void* d_ws, size_t ws_size,
                              hipStream_t stream) {
  const float* q  = (const float*)d_in[0];
  const float* k  = (const float*)d_in[1];
  const float* v  = (const float*)d_in[2];
  const float* Wq = (const float*)d_in[3];
  const float* bq = (const float*)d_in[4];
  const float* Wk = (const float*)d_in[5];
  const float* bk = (const float*)d_in[6];
  const float* Wv = (const float*)d_in[7];
  const float* bv = (const float*)d_in[8];
  float* out = (float*)d_out;

  const int B = 8, S = 2048, D = 1024;
  const long BS = (long)B * S;
  const long nQKV = BS * D;
  const long nW = (long)D * D;

  // d_out staging: qb/kb/vb bf16 [0,96M) (dead after vpT GEMM);
  // red_s_sum @96M (512KB), c_s @98M (64KB). final_emit overwrites d_out last.
  ushort* qb = (ushort*)d_out;
  ushort* kb = qb + nQKV;
  ushort* vb = kb + nQKV;
  float* red_s_sum = (float*)((char*)d_out + (96ull << 20));
  float* c_s       = (float*)((char*)d_out + (98ull << 20));

  // workspace map:
  //  [0,32M)  qp  -> (dead after scores)  vs
  //  [32,64M) kp  -> (dead after scores)  attnB
  //  [64,96M) vpT -> (dead after scale_v) red_f_max@64M, red_f_sum@65M, Mf@66M, Zf@67M
  //  [96,160M) Wqb/Wkb/Wvb (early) -> expS bf16 [b][q][k]
  char* ws = (char*)d_ws;
  ushort* qp     = (ushort*)ws;
  ushort* kp     = (ushort*)(ws + (32ull << 20));
  ushort* vpT    = (ushort*)(ws + (64ull << 20));
  ushort* Wqb    = (ushort*)(ws + (96ull << 20));
  ushort* Wkb    = Wqb + nW;
  ushort* Wvb    = Wkb + nW;
  ushort* expS   = (ushort*)(ws + (96ull << 20));
  ushort* vs     = (ushort*)ws;
  ushort* attnB  = (ushort*)(ws + (32ull << 20));
  float* red_f_max = (float*)(ws + (64ull << 20));
  float* red_f_sum = (float*)(ws + (65ull << 20));
  float* Mf        = (float*)(ws + (66ull << 20));
  float* Zf        = (float*)(ws + (67ull << 20));

  const int SH = 131072;
  (void)hipFuncSetAttribute(reinterpret_cast<const void*>(&gemm256<1,0,0,0>),
                            hipFuncAttributeMaxDynamicSharedMemorySize, SH);
  (void)hipFuncSetAttribute(reinterpret_cast<const void*>(&gemm256<2,0,0,0>),
                            hipFuncAttributeMaxDynamicSharedMemorySize, SH);
  (void)hipFuncSetAttribute(reinterpret_cast<const void*>(&gemm256<0,1,2,1>),
                            hipFuncAttributeMaxDynamicSharedMemorySize, SH);
  (void)hipFuncSetAttribute(reinterpret_cast<const void*>(&gemm256<0,0,1,0>),
                            hipFuncAttributeMaxDynamicSharedMemorySize, SH);

  // ---- conversions: 2 launches (weights; q/k/v) ----
  {
    int n4w = (int)(nW / 4);
    cvt3<<<dim3((n4w + 255) / 256, 3), 256, 0, stream>>>(
        (const float4*)Wq, (const float4*)Wk, (const float4*)Wv,
        (ushort4*)Wqb, (ushort4*)Wkb, (ushort4*)Wvb, n4w);
    int n4q = (int)(nQKV / 4);
    cvt3<<<dim3((n4q + 255) / 256, 3), 256, 0, stream>>>(
        (const float4*)q, (const float4*)k, (const float4*)v,
        (ushort4*)qb, (ushort4*)kb, (ushort4*)vb, n4q);
  }

  // qp[m][e] = q[m][:]·Wq[e][:] + bq[e]   (gm=64, gn=4)
  gemm256<1,0,0,0><<<dim3(64 * 4), 512, SH, stream>>>(
      qb, Wqb, qp, bq, nullptr, nullptr, D, D, 0, 0, 0, 1.f, 64, 4);
  gemm256<1,0,0,0><<<dim3(64 * 4), 512, SH, stream>>>(
      kb, Wkb, kp, bk, nullptr, nullptr, D, D, 0, 0, 0, 1.f, 64, 4);
  // vpT[b][e][s] = Wv[e][:]·v[b][s][:] + bv[e]   (gm=4, gn=8, batch 8)
  gemm256<2,0,0,0><<<dim3(4 * 8 * B), 512, SH, stream>>>(
      Wvb, vb, vpT, bv, nullptr, nullptr, S, D, 0, (long)S * D, (long)D * S, 1.f, 4, 8);
  // expS = exp(qp·kp^T / 1024) + fused column-sum partials   (gm=8, gn=8, batch 8)
  gemm256<0,1,2,1><<<dim3(8 * 8 * B), 512, SH, stream>>>(
      qp, kp, expS, nullptr, nullptr, red_s_sum,
      S, D, (long)S * D, (long)S * D, (long)S * S, 1.f / 1024.f, 8, 8);

  // c[b,k] = 1/colsum;  vs = vpT * c
  combine_c<<<dim3(S / 256, B), 256, 0, stream>>>(red_s_sum, c_s, S, 8);
  scale_v<<<dim3((int)(nQKV / (256 * 8))), 256, 0, stream>>>(vpT, c_s, vs, S, D * S);

  // attn = expS·vs^T (bf16) + fused final-softmax pass1   (gm=8, gn=4, batch 8)
  gemm256<0,0,1,0><<<dim3(8 * 4 * B), 512, SH, stream>>>(
      expS, vs, attnB, nullptr, red_f_max, red_f_sum,
      D, S, (long)S * S, (long)D * S, (long)S * D, 1.f, 8, 4);

  colsm_combine<<<dim3(D / 256, B), 256, 0, stream>>>(red_f_max, red_f_sum, Mf, Zf, D, 8);
  final_emit<<<dim3(1, B, 128), 256, 0, stream>>>(attnB, q, out, out + nQKV, Mf, Zf, S, D, 16);

  (void)in_sizes; (void)n_in; (void)out_size; (void)ws_size;
}

// Round 15
// 312.155 us; speedup vs baseline: 1.3704x; 1.2607x over previous
//
#include <hip/hip_runtime.h>

typedef __attribute__((ext_vector_type(2))) long lx2;
typedef __attribute__((ext_vector_type(4))) float f32x4;

__device__ __forceinline__ ushort f2bf(float f) {
  union { float f; unsigned u; } x; x.f = f;
  unsigned r = x.u + 0x7FFFu + ((x.u >> 16) & 1u);
  return (ushort)(r >> 16);
}
__device__ __forceinline__ float bf2f(ushort u) {
  union { unsigned u; float f; } x; x.u = ((unsigned)u) << 16;
  return x.f;
}

// ---------------- fp8 e4m3 encode/decode ----------------
#if defined(__has_builtin)
#if __has_builtin(__builtin_amdgcn_cvt_pk_fp8_f32) && __has_builtin(__builtin_amdgcn_cvt_f32_fp8)
#define HAVE_HW_FP8 1
#endif
#endif

#ifdef HAVE_HW_FP8
__device__ __forceinline__ uint pk4_fp8(float f0, float f1, float f2, float f3) {
  int r = __builtin_amdgcn_cvt_pk_fp8_f32(f0, f1, 0, false);
  r = __builtin_amdgcn_cvt_pk_fp8_f32(f2, f3, r, true);
  return (uint)r;
}
#define FP8DEC(dw, sel) __builtin_amdgcn_cvt_f32_fp8((int)(dw), (sel))
#else
// software OCP e4m3fn: value = (8+M)*2^(E-10) for E>=1; M*2^-9 subnormal; max 448.
__device__ __forceinline__ unsigned char f2e4m3(float f) {
  unsigned u = __float_as_uint(f);
  unsigned s = (u >> 24) & 0x80;
  float a = fabsf(f);
  if (a != a) return (unsigned char)(s | 0x7f);        // NaN
  if (a >= 448.f) return (unsigned char)(s | 0x7e);    // saturate to 448
  int ei;
  (void)frexpf(a, &ei);                                // a = m*2^ei, m in [0.5,1)
  int E = ei + 6;                                      // E=1 for a in [2^-6, 2^-5)
  if (E < 1) {                                         // subnormal: quantum 2^-9
    int ki = (int)rintf(a * 512.f);                    // 0..8
    if (ki >= 8) return (unsigned char)(s | 0x08);     // rounds up to min normal
    return (unsigned char)(s | ki);
  }
  float q = a * exp2f((float)(10 - E));                // in [8,16)
  int ki = (int)rintf(q);
  if (ki >= 16) { E++; ki = 8; }
  if (E > 15 || (E == 15 && ki > 14)) return (unsigned char)(s | 0x7e);
  return (unsigned char)(s | (E << 3) | (ki - 8));
}
__device__ __forceinline__ uint pk4_fp8(float f0, float f1, float f2, float f3) {
  return (uint)f2e4m3(f0) | ((uint)f2e4m3(f1) << 8) |
         ((uint)f2e4m3(f2) << 16) | ((uint)f2e4m3(f3) << 24);
}
__device__ __forceinline__ float e4m3dec(unsigned char b) {
  int E = (b >> 3) & 15, M = b & 7;
  float v = E ? ldexpf((float)(8 + M), E - 10) : ldexpf((float)M, -9);
  return (b & 0x80) ? -v : v;
}
#define FP8DEC(dw, sel) e4m3dec((unsigned char)(((dw) >> (8 * (sel))) & 0xff))
#endif

__device__ __forceinline__ void gload_lds16(const void* g, void* l) {
  __builtin_amdgcn_global_load_lds(
      (const __attribute__((address_space(1))) void*)g,
      (__attribute__((address_space(3))) void*)l, 16, 0, 0);
}

// ---------------- fp32 -> fp8, 3 tensors per launch, 8 elems/thread ----------------
__global__ __launch_bounds__(256) void cvt3_fp8(
    const float4* __restrict__ s0, const float4* __restrict__ s1,
    const float4* __restrict__ s2, uint2* __restrict__ d0,
    uint2* __restrict__ d1, uint2* __restrict__ d2, int n8) {
  int i = blockIdx.x * 256 + threadIdx.x;
  if (i >= n8) return;
  const float4* s = blockIdx.y == 0 ? s0 : (blockIdx.y == 1 ? s1 : s2);
  uint2* d = blockIdx.y == 0 ? d0 : (blockIdx.y == 1 ? d1 : d2);
  float4 x = s[i * 2], y = s[i * 2 + 1];
  uint2 o;
  o.x = pk4_fp8(x.x, x.y, x.z, x.w);
  o.y = pk4_fp8(y.x, y.y, y.z, y.w);
  d[i] = o;
}

// ============ 256x256 16-wave fp8 GEMM (B^T form), 1 barrier / K-tile ============
// C[m,n] = f((sum_k A[m,k]*B[n,k])*(SCALED?scale:1) + bias), f=exp if EXPOUT
// 1024 thr = 16 waves (4m x 4n), per-wave 64x64 (acc[4][4]). BK=64.
// LDS 64KB: buf c: A chunks 0-15 @ c*32768 + r*1024, B @ +16384.
// Chunk r = rows r*16..+15, 64 k, lane-major: lane l holds 16B contiguous global
// (row r*16+(l&15), k k0+(l>>4)*16) at chunkbase+l*16 -> gload_lds16 direct;
// ds_read_b128 -> lx2, .x/.y = low/high 8 k-bytes (same consistent k-permutation
// for A and B -> MFMA-valid). mfma_f32_16x16x32_fp8_fp8 (bf16 rate, C/D layout
// identical, dtype-independent).
// Per K-tile: { vmcnt(0) [my 2 stages, 1-tile distance] | bar | stage t+1
//   (2 gloads/wave) | 8 ds_read | lgkm0 | setprio(1) 32 MFMA setprio(0) }.
// 4 waves/SIMD (VGPR<=128, LDS 64KB) hide barrier/LDS stalls.
// Epilogue: C staged to LDS bf16 (XOR 32B-slot swizzle) in 2x 128-row halves,
// coalesced flush; OUT_FP8 converts on flush (8 bf16 -> 8 fp8 / lane).
// REDUCE: 0 none; 1 col max+sumexp partials; 2 col plain-sum partials.
template<int BIAS_MODE, int SCALED, int REDUCE, int EXPOUT, int OUT_FP8>
__global__ __launch_bounds__(1024, 4) void gemmF(
    const unsigned char* __restrict__ A, const unsigned char* __restrict__ B,
    void* __restrict__ Cv, const float* __restrict__ bias,
    float* __restrict__ red_max, float* __restrict__ red_sum,
    int N, int K, long sA, long sB, long sC, float scale, int gm, int gn)
{
  extern __shared__ unsigned char lds[];   // 65536 B

  // ---- tile decode: bijective XCD swizzle + banded order ----
  const int nwg = gridDim.x;
  const int wg = blockIdx.x;
  const int cpx = nwg >> 3;
  const int wid_ = (wg & 7) * cpx + (wg >> 3);
  const int tiles = gm * gn;
  const int bz = wid_ / tiles;
  const int t2 = wid_ - bz * tiles;
  const int band = t2 / (gm << 2);
  const int r2 = t2 - band * (gm << 2);
  const int tile_m = (r2 >> 2) * 256;
  const int tile_n = ((band << 2) + (r2 & 3)) * 256;

  const unsigned char* Ab = A + (size_t)bz * sA;
  const unsigned char* Bb = B + (size_t)bz * sB;
  const int t = threadIdx.x;
  const int lane = t & 63;
  const int w = t >> 6;        // 0..15
  const int wr = w >> 2;       // 0..3
  const int wc = w & 3;        // 0..3

  f32x4 acc[4][4] = {};

#define STAGE(c, k0)                                                                   \
  do {                                                                                 \
    gload_lds16(Ab + (size_t)(tile_m + w * 16 + (lane & 15)) * K + (k0) +              \
                    (lane >> 4) * 16,                                                  \
                lds + (c) * 32768 + w * 1024);                                         \
    gload_lds16(Bb + (size_t)(tile_n + w * 16 + (lane & 15)) * K + (k0) +              \
                    (lane >> 4) * 16,                                                  \
                lds + (c) * 32768 + 16384 + w * 1024);                                 \
  } while (0)

  // ---- prologue ----
  STAGE(0, 0);

  const int KT = K >> 6;
  for (int tt = 0; tt < KT; ++tt) {
    const int c = tt & 1;
    asm volatile("s_waitcnt vmcnt(0)" ::: "memory");   // tile tt's 2 stages (1-tile dist)
    __builtin_amdgcn_s_barrier();                      // publish all waves' stages
    if (tt + 1 < KT) STAGE(c ^ 1, (tt + 1) << 6);
    lx2 aA[4], bB[4];
#pragma unroll
    for (int mi = 0; mi < 4; ++mi)
      aA[mi] = *(const lx2*)(lds + c * 32768 + (wr * 4 + mi) * 1024 + lane * 16);
#pragma unroll
    for (int nf = 0; nf < 4; ++nf)
      bB[nf] = *(const lx2*)(lds + c * 32768 + 16384 + (wc * 4 + nf) * 1024 + lane * 16);
    asm volatile("s_waitcnt lgkmcnt(0)" ::: "memory");
    __builtin_amdgcn_sched_barrier(0);
    __builtin_amdgcn_s_setprio(1);
#pragma unroll
    for (int kk = 0; kk < 2; ++kk)
#pragma unroll
      for (int mi = 0; mi < 4; ++mi)
#pragma unroll
        for (int nf = 0; nf < 4; ++nf)
          acc[mi][nf] = __builtin_amdgcn_mfma_f32_16x16x32_fp8_fp8(
              aA[mi][kk], bB[nf][kk], acc[mi][nf], 0, 0, 0);
    __builtin_amdgcn_s_setprio(0);
  }
#undef STAGE

  // ---- epilogue: 2 half-passes (128 rows) via LDS bf16, swizzled ----
  float sm2[4] = {0.f, 0.f, 0.f, 0.f};
  const int g5 = ((lane >> 4) & 3) << 5;
  int ccl[4]; float bcn[4];
#pragma unroll
  for (int nf = 0; nf < 4; ++nf) {
    ccl[nf] = wc * 64 + nf * 16 + (lane & 15);
    bcn[nf] = (BIAS_MODE == 1) ? bias[tile_n + ccl[nf]] : 0.f;
  }
#pragma unroll
  for (int h = 0; h < 2; ++h) {
    __syncthreads();
    if ((wr >> 1) == h) {
#pragma unroll
      for (int mi = 0; mi < 4; ++mi) {
#pragma unroll
        for (int j = 0; j < 4; ++j) {
          const int row = (wr & 1) * 64 + mi * 16 + ((lane >> 4) << 2) + j;  // 0..127
          float bcr = (BIAS_MODE == 2) ? bias[tile_m + h * 128 + row] : 0.f;
#pragma unroll
          for (int nf = 0; nf < 4; ++nf) {
            float val = acc[mi][nf][j];
            if (SCALED) val *= scale;
            if (BIAS_MODE == 1) val += bcn[nf];
            else if (BIAS_MODE == 2) val += bcr;
            if (EXPOUT) val = __expf(val);
            if (REDUCE == 2) sm2[nf] += val;
            *(ushort*)(lds + row * 512 + ((ccl[nf] * 2) ^ g5)) = f2bf(val);
          }
        }
      }
    }
    __syncthreads();
    // coalesced flush: 4 passes x 1024 thr x 16B LDS
#pragma unroll
    for (int p = 0; p < 4; ++p) {
      int off = p * 16384 + t * 16;
      int row = off >> 9;
      int b = off & 511;
      int bs = b ^ (((row >> 2) & 3) << 5);
      f32x4 d = *(const f32x4*)(lds + row * 512 + bs);
      const int gr = tile_m + h * 128 + row;
      if (OUT_FP8) {
        const uint* dw = (const uint*)&d;
        float f0 = bf2f((ushort)(dw[0] & 0xffff)), f1 = bf2f((ushort)(dw[0] >> 16));
        float f2 = bf2f((ushort)(dw[1] & 0xffff)), f3 = bf2f((ushort)(dw[1] >> 16));
        float f4 = bf2f((ushort)(dw[2] & 0xffff)), f5 = bf2f((ushort)(dw[2] >> 16));
        float f6 = bf2f((ushort)(dw[3] & 0xffff)), f7 = bf2f((ushort)(dw[3] >> 16));
        uint2 o;
        o.x = pk4_fp8(f0, f1, f2, f3);
        o.y = pk4_fp8(f4, f5, f6, f7);
        *(uint2*)((unsigned char*)Cv + (size_t)bz * sC + (size_t)gr * N + tile_n + (b >> 1)) = o;
      } else {
        *(f32x4*)((ushort*)Cv + (size_t)bz * sC + (size_t)gr * N + tile_n + (b >> 1)) = d;
      }
    }
  }

  if constexpr (REDUCE == 2) {
    __syncthreads();
    float* sb = (float*)lds;   // [4][256]
#pragma unroll
    for (int nf = 0; nf < 4; ++nf) {
      float s1 = sm2[nf] + __shfl_xor(sm2[nf], 16);
      float Ss = s1 + __shfl_xor(s1, 32);
      if ((lane >> 4) == nf) sb[wr * 256 + ccl[nf]] = Ss;
    }
    __syncthreads();
    if (t < 256) {
      size_t rb = ((size_t)bz * gm + (tile_m >> 8)) * N + tile_n + t;
      red_sum[rb] = sb[t] + sb[256 + t] + sb[512 + t] + sb[768 + t];
    }
  }
  if constexpr (REDUCE == 1) {
    __syncthreads();
    float* mb = (float*)lds;          // [4][256]
    float* sb = (float*)lds + 1024;   // [4][256]
#pragma unroll
    for (int nf = 0; nf < 4; ++nf) {
      float mx = -1e30f;
#pragma unroll
      for (int mi = 0; mi < 4; ++mi)
#pragma unroll
        for (int j = 0; j < 4; ++j) {
          float val = acc[mi][nf][j];
          if (SCALED) val *= scale;
          mx = fmaxf(mx, val);
        }
      float m1 = fmaxf(mx, __shfl_xor(mx, 16));
      float M = fmaxf(m1, __shfl_xor(m1, 32));
      float sm = 0.f;
#pragma unroll
      for (int mi = 0; mi < 4; ++mi)
#pragma unroll
        for (int j = 0; j < 4; ++j) {
          float val = acc[mi][nf][j];
          if (SCALED) val *= scale;
          sm += __expf(val - M);
        }
      float s1 = sm + __shfl_xor(sm, 16);
      float Ss = s1 + __shfl_xor(s1, 32);
      if ((lane >> 4) == nf) {
        mb[wr * 256 + ccl[nf]] = M;
        sb[wr * 256 + ccl[nf]] = Ss;
      }
    }
    __syncthreads();
    if (t < 256) {
      float M = fmaxf(fmaxf(mb[t], mb[256 + t]), fmaxf(mb[512 + t], mb[768 + t]));
      float Ss = sb[t] * __expf(mb[t] - M) + sb[256 + t] * __expf(mb[256 + t] - M) +
                 sb[512 + t] * __expf(mb[512 + t] - M) + sb[768 + t] * __expf(mb[768 + t] - M);
      size_t rb = ((size_t)bz * gm + (tile_m >> 8)) * N + tile_n + t;
      red_max[rb] = M;
      red_sum[rb] = Ss;
    }
  }
}

// c[b,k] = 1024 / sum_ch red_sum[b][ch][k]   (x1024 keeps vs in fp8 range)
__global__ __launch_bounds__(256) void combine_c(
    const float* __restrict__ red_sum, float* __restrict__ cvec, int cols, int nch)
{
  const int b = blockIdx.y;
  const int c = blockIdx.x * 256 + threadIdx.x;
  float Z = 0.f;
  for (int ch = 0; ch < nch; ++ch)
    Z += red_sum[((size_t)b * nch + ch) * cols + c];
  cvec[(size_t)b * cols + c] = 1024.f / Z;
}

// vs[b][d][k] = fp8( vpT_fp8[b][d][k] * c[b][k] )   (8 elems/thread)
__global__ __launch_bounds__(256) void scale_v(
    const uint2* __restrict__ vpT, const float* __restrict__ cvec,
    uint2* __restrict__ vs, int S, long DS)
{
  const size_t i8 = (size_t)blockIdx.x * 256 + threadIdx.x;
  const size_t k8 = i8 * 8;
  const int b = (int)(k8 / DS);
  const int kcol = (int)(k8 % S);
  uint2 u = vpT[i8];
  const float* cb = cvec + (size_t)b * S + kcol;
  float f0 = FP8DEC(u.x, 0) * cb[0], f1 = FP8DEC(u.x, 1) * cb[1];
  float f2 = FP8DEC(u.x, 2) * cb[2], f3 = FP8DEC(u.x, 3) * cb[3];
  float f4 = FP8DEC(u.y, 0) * cb[4], f5 = FP8DEC(u.y, 1) * cb[5];
  float f6 = FP8DEC(u.y, 2) * cb[6], f7 = FP8DEC(u.y, 3) * cb[7];
  uint2 o;
  o.x = pk4_fp8(f0, f1, f2, f3);
  o.y = pk4_fp8(f4, f5, f6, f7);
  vs[i8] = o;
}

// combine partials -> M, 1/Z per (b,col). grid: (cols/256, B)
__global__ __launch_bounds__(256) void colsm_combine(
    const float* __restrict__ red_max, const float* __restrict__ red_sum,
    float* __restrict__ Mv, float* __restrict__ Zinv, int cols, int nch)
{
  const int b = blockIdx.y;
  const int c = blockIdx.x * 256 + threadIdx.x;
  float M = -1e30f, Z = 0.f;
  for (int ch = 0; ch < nch; ++ch) {
    size_t o = ((size_t)b * nch + ch) * cols + c;
    float m = red_max[o], s = red_sum[o];
    float nm = fmaxf(M, m);
    Z = Z * __expf(M - nm) + s * __expf(m - nm);
    M = nm;
  }
  Mv[(size_t)b * cols + c] = M;
  Zinv[(size_t)b * cols + c] = 1.f / Z;
}

// final: out1 = softmax(attn over rows), out0 = attn + residual. attn is bf16.
__global__ __launch_bounds__(256) void final_emit(
    const ushort* __restrict__ attnB, const float* __restrict__ q,
    float* __restrict__ out0, float* __restrict__ out1,
    const float* __restrict__ Mv, const float* __restrict__ Zinv,
    int rows, int cols, int rpc)
{
  const int b = blockIdx.y;
  const int ch = blockIdx.z;
  const size_t base = (size_t)b * rows * cols;
  const int c4 = (blockIdx.x * 256 + threadIdx.x) * 4;
  const int r0 = ch * rpc;
  float M[4], Zi[4];
#pragma unroll
  for (int i = 0; i < 4; ++i) {
    M[i] = Mv[(size_t)b * cols + c4 + i];
    Zi[i] = Zinv[(size_t)b * cols + c4 + i];
  }
  for (int r = r0; r < r0 + rpc; ++r) {
    size_t o = base + (size_t)r * cols + c4;
    ushort4 u = *(const ushort4*)(attnB + o);
    float4 qv = *(const float4*)(q + o);
    float a0 = bf2f(u.x), a1 = bf2f(u.y), a2 = bf2f(u.z), a3 = bf2f(u.w);
    float4 wv, s;
    wv.x = __expf(a0 - M[0]) * Zi[0];
    wv.y = __expf(a1 - M[1]) * Zi[1];
    wv.z = __expf(a2 - M[2]) * Zi[2];
    wv.w = __expf(a3 - M[3]) * Zi[3];
    s.x = a0 + qv.x; s.y = a1 + qv.y; s.z = a2 + qv.z; s.w = a3 + qv.w;
    *(float4*)(out1 + o) = wv;
    *(float4*)(out0 + o) = s;
  }
}

extern "C" void kernel_launch(void* const* d_in, const int* in_sizes, int n_in,
                              void* d_out, int out_size, void* d_ws, size_t ws_size,
                              hipStream_t stream) {
  const float* q  = (const float*)d_in[0];
  const float* k  = (const float*)d_in[1];
  const float* v  = (const float*)d_in[2];
  const float* Wq = (const float*)d_in[3];
  const float* bq = (const float*)d_in[4];
  const float* Wk = (const float*)d_in[5];
  const float* bk = (const float*)d_in[6];
  const float* Wv = (const float*)d_in[7];
  const float* bv = (const float*)d_in[8];
  float* out = (float*)d_out;

  const int B = 8, S = 2048, D = 1024;
  const long BS = (long)B * S;
  const long nQKV = BS * D;        // 16.7M elems
  const long nW = (long)D * D;

  // d_out staging (fp8): qb [0,16M), kb [16,32M), vb [32,48M),
  // Wq8/Wk8/Wv8 @48/49/50M; red_s_sum @64M (512KB); c_s @66M (64KB).
  // final_emit overwrites all of d_out at the end.
  unsigned char* qb8 = (unsigned char*)d_out;
  unsigned char* kb8 = qb8 + nQKV;
  unsigned char* vb8 = kb8 + nQKV;
  unsigned char* Wq8 = (unsigned char*)d_out + (48ull << 20);
  unsigned char* Wk8 = (unsigned char*)d_out + (49ull << 20);
  unsigned char* Wv8 = (unsigned char*)d_out + (50ull << 20);
  float* red_s_sum = (float*)((char*)d_out + (64ull << 20));
  float* c_s       = (float*)((char*)d_out + (66ull << 20));

  // ws: qp8 [0,16M), kp8 [16,32M), vpT8 [32,48M), vs8 [48,64M),
  //     expS8 [64,96M), attnB bf16 [96,128M), red_f/Mf/Zf @128M+.
  char* ws = (char*)d_ws;
  unsigned char* qp8   = (unsigned char*)ws;
  unsigned char* kp8   = (unsigned char*)(ws + (16ull << 20));
  unsigned char* vpT8  = (unsigned char*)(ws + (32ull << 20));
  unsigned char* vs8   = (unsigned char*)(ws + (48ull << 20));
  unsigned char* expS8 = (unsigned char*)(ws + (64ull << 20));
  ushort* attnB        = (ushort*)(ws + (96ull << 20));
  float* red_f_max = (float*)(ws + (128ull << 20));
  float* red_f_sum = (float*)(ws + (129ull << 20));
  float* Mf        = (float*)(ws + (130ull << 20));
  float* Zf        = (float*)(ws + (131ull << 20));

  const int SH = 65536;
  (void)hipFuncSetAttribute(reinterpret_cast<const void*>(&gemmF<1,0,0,0,1>),
                            hipFuncAttributeMaxDynamicSharedMemorySize, SH);
  (void)hipFuncSetAttribute(reinterpret_cast<const void*>(&gemmF<2,0,0,0,1>),
                            hipFuncAttributeMaxDynamicSharedMemorySize, SH);
  (void)hipFuncSetAttribute(reinterpret_cast<const void*>(&gemmF<0,1,2,1,1>),
                            hipFuncAttributeMaxDynamicSharedMemorySize, SH);
  (void)hipFuncSetAttribute(reinterpret_cast<const void*>(&gemmF<0,1,1,0,0>),
                            hipFuncAttributeMaxDynamicSharedMemorySize, SH);

  // ---- fp32 -> fp8 conversions: 2 launches (weights; q/k/v) ----
  {
    int n8w = (int)(nW / 8);
    cvt3_fp8<<<dim3((n8w + 255) / 256, 3), 256, 0, stream>>>(
        (const float4*)Wq, (const float4*)Wk, (const float4*)Wv,
        (uint2*)Wq8, (uint2*)Wk8, (uint2*)Wv8, n8w);
    int n8q = (int)(nQKV / 8);
    cvt3_fp8<<<dim3((n8q + 255) / 256, 3), 256, 0, stream>>>(
        (const float4*)q, (const float4*)k, (const float4*)v,
        (uint2*)qb8, (uint2*)kb8, (uint2*)vb8, n8q);
  }

  // qp[m][e] = q·Wq + bq (fp8 out)   gm=64, gn=4 -> 256 blocks
  gemmF<1,0,0,0,1><<<dim3(64 * 4), 1024, SH, stream>>>(
      qb8, Wq8, qp8, bq, nullptr, nullptr, D, D, 0, 0, 0, 1.f, 64, 4);
  gemmF<1,0,0,0,1><<<dim3(64 * 4), 1024, SH, stream>>>(
      kb8, Wk8, kp8, bk, nullptr, nullptr, D, D, 0, 0, 0, 1.f, 64, 4);
  // vpT[b][e][s] = Wv·v^T + bv (row bias, fp8 out)   gm=4, gn=8, batch 8
  gemmF<2,0,0,0,1><<<dim3(4 * 8 * B), 1024, SH, stream>>>(
      Wv8, vb8, vpT8, bv, nullptr, nullptr, S, D, 0, (long)S * D, (long)D * S, 1.f, 4, 8);
  // expS = exp(qp·kp^T / 1024) (fp8 out) + fused col-sum partials   gm=8, gn=8, b8
  gemmF<0,1,2,1,1><<<dim3(8 * 8 * B), 1024, SH, stream>>>(
      qp8, kp8, expS8, nullptr, nullptr, red_s_sum,
      S, D, (long)S * D, (long)S * D, (long)S * S, 1.f / 1024.f, 8, 8);

  // c = 1024/colsum;  vs = vpT * c  (fp8)
  combine_c<<<dim3(S / 256, B), 256, 0, stream>>>(red_s_sum, c_s, S, 8);
  scale_v<<<dim3((int)(nQKV / (256 * 8))), 256, 0, stream>>>(
      (const uint2*)vpT8, c_s, (uint2*)vs8, S, (long)D * S);

  // attn = (expS·vs^T)/1024 (bf16 out) + fused final-softmax pass1  gm=8, gn=4, b8
  gemmF<0,1,1,0,0><<<dim3(8 * 4 * B), 1024, SH, stream>>>(
      expS8, vs8, attnB, nullptr, red_f_max, red_f_sum,
      D, S, (long)S * S, (long)D * S, (long)S * D, 1.f / 1024.f, 8, 4);

  colsm_combine<<<dim3(D / 256, B), 256, 0, stream>>>(red_f_max, red_f_sum, Mf, Zf, D, 8);
  final_emit<<<dim3(1, B, 128), 256, 0, stream>>>(attnB, q, out, out + nQKV, Mf, Zf, S, D, 16);

  (void)in_sizes; (void)n_in; (void)out_size; (void)ws_size;
}

// Round 17
// 312.120 us; speedup vs baseline: 1.3706x; 1.0001x over previous
//
#include <hip/hip_runtime.h>

typedef __attribute__((ext_vector_type(2))) long lx2;
typedef __attribute__((ext_vector_type(4))) float f32x4;

__device__ __forceinline__ ushort f2bf(float f) {
  union { float f; unsigned u; } x; x.f = f;
  unsigned r = x.u + 0x7FFFu + ((x.u >> 16) & 1u);
  return (ushort)(r >> 16);
}
__device__ __forceinline__ float bf2f(ushort u) {
  union { unsigned u; float f; } x; x.u = ((unsigned)u) << 16;
  return x.f;
}

// ---------------- fp8 e4m3 encode/decode ----------------
#if defined(__has_builtin)
#if __has_builtin(__builtin_amdgcn_cvt_pk_fp8_f32) && __has_builtin(__builtin_amdgcn_cvt_f32_fp8)
#define HAVE_HW_FP8 1
#endif
#endif

#ifdef HAVE_HW_FP8
__device__ __forceinline__ uint pk4_fp8(float f0, float f1, float f2, float f3) {
  int r = __builtin_amdgcn_cvt_pk_fp8_f32(f0, f1, 0, false);
  r = __builtin_amdgcn_cvt_pk_fp8_f32(f2, f3, r, true);
  return (uint)r;
}
#define FP8DEC(dw, sel) __builtin_amdgcn_cvt_f32_fp8((int)(dw), (sel))
#else
// software OCP e4m3fn: value = (8+M)*2^(E-10) for E>=1; M*2^-9 subnormal; max 448.
__device__ __forceinline__ unsigned char f2e4m3(float f) {
  unsigned u = __float_as_uint(f);
  unsigned s = (u >> 24) & 0x80;
  float a = fabsf(f);
  if (a != a) return (unsigned char)(s | 0x7f);        // NaN
  if (a >= 448.f) return (unsigned char)(s | 0x7e);    // saturate to 448
  int ei;
  (void)frexpf(a, &ei);                                // a = m*2^ei, m in [0.5,1)
  int E = ei + 6;                                      // E=1 for a in [2^-6, 2^-5)
  if (E < 1) {                                         // subnormal: quantum 2^-9
    int ki = (int)rintf(a * 512.f);                    // 0..8
    if (ki >= 8) return (unsigned char)(s | 0x08);     // rounds up to min normal
    return (unsigned char)(s | ki);
  }
  float q = a * exp2f((float)(10 - E));                // in [8,16)
  int ki = (int)rintf(q);
  if (ki >= 16) { E++; ki = 8; }
  if (E > 15 || (E == 15 && ki > 14)) return (unsigned char)(s | 0x7e);
  return (unsigned char)(s | (E << 3) | (ki - 8));
}
__device__ __forceinline__ uint pk4_fp8(float f0, float f1, float f2, float f3) {
  return (uint)f2e4m3(f0) | ((uint)f2e4m3(f1) << 8) |
         ((uint)f2e4m3(f2) << 16) | ((uint)f2e4m3(f3) << 24);
}
__device__ __forceinline__ float e4m3dec(unsigned char b) {
  int E = (b >> 3) & 15, M = b & 7;
  float v = E ? ldexpf((float)(8 + M), E - 10) : ldexpf((float)M, -9);
  return (b & 0x80) ? -v : v;
}
#define FP8DEC(dw, sel) e4m3dec((unsigned char)(((dw) >> (8 * (sel))) & 0xff))
#endif

__device__ __forceinline__ void gload_lds16(const void* g, void* l) {
  __builtin_amdgcn_global_load_lds(
      (const __attribute__((address_space(1))) void*)g,
      (__attribute__((address_space(3))) void*)l, 16, 0, 0);
}

// ------- fp32 -> fp8, wave-coalesced: wave owns 1024 contiguous elems -------
// 4 loads/lane: f[j] at wave_base + j*256 + lane*4 (16B/lane, coalesced 1KB/inst);
// 4 stores: d[wave_base/4 + j*64 + lane] (4B/lane, coalesced 256B/inst).
// Coverage exact: 4x256 elems loaded = 4x64 uints stored. grid: (n/4096, 3).
__global__ __launch_bounds__(256) void cvt3_fp8(
    const float* __restrict__ s0, const float* __restrict__ s1,
    const float* __restrict__ s2, uint* __restrict__ d0,
    uint* __restrict__ d1, uint* __restrict__ d2, long n) {
  const float* s = blockIdx.y == 0 ? s0 : (blockIdx.y == 1 ? s1 : s2);
  uint* d = blockIdx.y == 0 ? d0 : (blockIdx.y == 1 ? d1 : d2);
  const int lane = threadIdx.x & 63;
  const int w = threadIdx.x >> 6;
  const long wave_base = ((long)blockIdx.x * 4 + w) * 1024;
  if (wave_base >= n) return;
  float4 f[4];
#pragma unroll
  for (int j = 0; j < 4; ++j)
    f[j] = *(const float4*)(s + wave_base + j * 256 + lane * 4);
#pragma unroll
  for (int j = 0; j < 4; ++j)
    d[(wave_base >> 2) + j * 64 + lane] = pk4_fp8(f[j].x, f[j].y, f[j].z, f[j].w);
}

// ============ 256x256 16-wave fp8 GEMM (B^T form), 1 barrier / K-tile ============
// C[m,n] = f((sum_k A[m,k]*B[n,k])*(SCALED?scale:1) + bias), f=exp if EXPOUT
// 1024 thr = 16 waves (4m x 4n), per-wave 64x64 (acc[4][4]). BK=64.
// LDS 64KB: buf c: A chunks 0-15 @ c*32768 + r*1024, B @ +16384.
// Chunk r = rows r*16..+15, 64 k, lane-major: lane l holds 16B contiguous global
// (row r*16+(l&15), k k0+(l>>4)*16) at chunkbase+l*16 -> gload_lds16 direct;
// ds_read_b128 -> lx2, .x/.y = low/high 8 k-bytes (same consistent k-permutation
// for A and B -> MFMA-valid). mfma_f32_16x16x32_fp8_fp8 (bf16 rate, C/D layout
// identical, dtype-independent).
// Per K-tile: { vmcnt(0) [my 2 stages, 1-tile distance] | bar | stage t+1
//   (2 gloads/wave) | 8 ds_read | lgkm0 | setprio(1) 32 MFMA setprio(0) }.
// 4 waves/SIMD (VGPR<=128, LDS 64KB) hide barrier/LDS stalls.
// Epilogue: C staged to LDS bf16 (XOR 32B-slot swizzle) in 2x 128-row halves,
// coalesced flush; OUT_FP8 converts on flush (8 bf16 -> 8 fp8 / lane).
// REDUCE: 0 none; 1 col max+sumexp partials; 2 col plain-sum partials.
template<int BIAS_MODE, int SCALED, int REDUCE, int EXPOUT, int OUT_FP8>
__global__ __launch_bounds__(1024, 4) void gemmF(
    const unsigned char* __restrict__ A, const unsigned char* __restrict__ B,
    void* __restrict__ Cv, const float* __restrict__ bias,
    float* __restrict__ red_max, float* __restrict__ red_sum,
    int N, int K, long sA, long sB, long sC, float scale, int gm, int gn)
{
  extern __shared__ unsigned char lds[];   // 65536 B

  // ---- tile decode: bijective XCD swizzle + banded order ----
  const int nwg = gridDim.x;
  const int wg = blockIdx.x;
  const int cpx = nwg >> 3;
  const int wid_ = (wg & 7) * cpx + (wg >> 3);
  const int tiles = gm * gn;
  const int bz = wid_ / tiles;
  const int t2 = wid_ - bz * tiles;
  const int band = t2 / (gm << 2);
  const int r2 = t2 - band * (gm << 2);
  const int tile_m = (r2 >> 2) * 256;
  const int tile_n = ((band << 2) + (r2 & 3)) * 256;

  const unsigned char* Ab = A + (size_t)bz * sA;
  const unsigned char* Bb = B + (size_t)bz * sB;
  const int t = threadIdx.x;
  const int lane = t & 63;
  const int w = t >> 6;        // 0..15
  const int wr = w >> 2;       // 0..3
  const int wc = w & 3;        // 0..3

  f32x4 acc[4][4] = {};

#define STAGE(c, k0)                                                                   \
  do {                                                                                 \
    gload_lds16(Ab + (size_t)(tile_m + w * 16 + (lane & 15)) * K + (k0) +              \
                    (lane >> 4) * 16,                                                  \
                lds + (c) * 32768 + w * 1024);                                         \
    gload_lds16(Bb + (size_t)(tile_n + w * 16 + (lane & 15)) * K + (k0) +              \
                    (lane >> 4) * 16,                                                  \
                lds + (c) * 32768 + 16384 + w * 1024);                                 \
  } while (0)

  // ---- prologue ----
  STAGE(0, 0);

  const int KT = K >> 6;
  for (int tt = 0; tt < KT; ++tt) {
    const int c = tt & 1;
    asm volatile("s_waitcnt vmcnt(0)" ::: "memory");   // tile tt's 2 stages (1-tile dist)
    __builtin_amdgcn_s_barrier();                      // publish all waves' stages
    if (tt + 1 < KT) STAGE(c ^ 1, (tt + 1) << 6);
    lx2 aA[4], bB[4];
#pragma unroll
    for (int mi = 0; mi < 4; ++mi)
      aA[mi] = *(const lx2*)(lds + c * 32768 + (wr * 4 + mi) * 1024 + lane * 16);
#pragma unroll
    for (int nf = 0; nf < 4; ++nf)
      bB[nf] = *(const lx2*)(lds + c * 32768 + 16384 + (wc * 4 + nf) * 1024 + lane * 16);
    asm volatile("s_waitcnt lgkmcnt(0)" ::: "memory");
    __builtin_amdgcn_sched_barrier(0);
    __builtin_amdgcn_s_setprio(1);
#pragma unroll
    for (int kk = 0; kk < 2; ++kk)
#pragma unroll
      for (int mi = 0; mi < 4; ++mi)
#pragma unroll
        for (int nf = 0; nf < 4; ++nf)
          acc[mi][nf] = __builtin_amdgcn_mfma_f32_16x16x32_fp8_fp8(
              aA[mi][kk], bB[nf][kk], acc[mi][nf], 0, 0, 0);
    __builtin_amdgcn_s_setprio(0);
  }
#undef STAGE

  // ---- epilogue: 2 half-passes (128 rows) via LDS bf16, swizzled ----
  float sm2[4] = {0.f, 0.f, 0.f, 0.f};
  const int g5 = ((lane >> 4) & 3) << 5;
  int ccl[4]; float bcn[4];
#pragma unroll
  for (int nf = 0; nf < 4; ++nf) {
    ccl[nf] = wc * 64 + nf * 16 + (lane & 15);
    bcn[nf] = (BIAS_MODE == 1) ? bias[tile_n + ccl[nf]] : 0.f;
  }
#pragma unroll
  for (int h = 0; h < 2; ++h) {
    __syncthreads();
    if ((wr >> 1) == h) {
#pragma unroll
      for (int mi = 0; mi < 4; ++mi) {
#pragma unroll
        for (int j = 0; j < 4; ++j) {
          const int row = (wr & 1) * 64 + mi * 16 + ((lane >> 4) << 2) + j;  // 0..127
          float bcr = (BIAS_MODE == 2) ? bias[tile_m + h * 128 + row] : 0.f;
#pragma unroll
          for (int nf = 0; nf < 4; ++nf) {
            float val = acc[mi][nf][j];
            if (SCALED) val *= scale;
            if (BIAS_MODE == 1) val += bcn[nf];
            else if (BIAS_MODE == 2) val += bcr;
            if (EXPOUT) val = __expf(val);
            if (REDUCE == 2) sm2[nf] += val;
            *(ushort*)(lds + row * 512 + ((ccl[nf] * 2) ^ g5)) = f2bf(val);
          }
        }
      }
    }
    __syncthreads();
    // coalesced flush: 4 passes x 1024 thr x 16B LDS
#pragma unroll
    for (int p = 0; p < 4; ++p) {
      int off = p * 16384 + t * 16;
      int row = off >> 9;
      int b = off & 511;
      int bs = b ^ (((row >> 2) & 3) << 5);
      f32x4 d = *(const f32x4*)(lds + row * 512 + bs);
      const int gr = tile_m + h * 128 + row;
      if (OUT_FP8) {
        const uint* dw = (const uint*)&d;
        float f0 = bf2f((ushort)(dw[0] & 0xffff)), f1 = bf2f((ushort)(dw[0] >> 16));
        float f2 = bf2f((ushort)(dw[1] & 0xffff)), f3 = bf2f((ushort)(dw[1] >> 16));
        float f4 = bf2f((ushort)(dw[2] & 0xffff)), f5 = bf2f((ushort)(dw[2] >> 16));
        float f6 = bf2f((ushort)(dw[3] & 0xffff)), f7 = bf2f((ushort)(dw[3] >> 16));
        uint2 o;
        o.x = pk4_fp8(f0, f1, f2, f3);
        o.y = pk4_fp8(f4, f5, f6, f7);
        *(uint2*)((unsigned char*)Cv + (size_t)bz * sC + (size_t)gr * N + tile_n + (b >> 1)) = o;
      } else {
        *(f32x4*)((ushort*)Cv + (size_t)bz * sC + (size_t)gr * N + tile_n + (b >> 1)) = d;
      }
    }
  }

  if constexpr (REDUCE == 2) {
    __syncthreads();
    float* sb = (float*)lds;   // [4][256]
#pragma unroll
    for (int nf = 0; nf < 4; ++nf) {
      float s1 = sm2[nf] + __shfl_xor(sm2[nf], 16);
      float Ss = s1 + __shfl_xor(s1, 32);
      if ((lane >> 4) == nf) sb[wr * 256 + ccl[nf]] = Ss;
    }
    __syncthreads();
    if (t < 256) {
      size_t rb = ((size_t)bz * gm + (tile_m >> 8)) * N + tile_n + t;
      red_sum[rb] = sb[t] + sb[256 + t] + sb[512 + t] + sb[768 + t];
    }
  }
  if constexpr (REDUCE == 1) {
    __syncthreads();
    float* mb = (float*)lds;          // [4][256]
    float* sb = (float*)lds + 1024;   // [4][256]
#pragma unroll
    for (int nf = 0; nf < 4; ++nf) {
      float mx = -1e30f;
#pragma unroll
      for (int mi = 0; mi < 4; ++mi)
#pragma unroll
        for (int j = 0; j < 4; ++j) {
          float val = acc[mi][nf][j];
          if (SCALED) val *= scale;
          mx = fmaxf(mx, val);
        }
      float m1 = fmaxf(mx, __shfl_xor(mx, 16));
      float M = fmaxf(m1, __shfl_xor(m1, 32));
      float sm = 0.f;
#pragma unroll
      for (int mi = 0; mi < 4; ++mi)
#pragma unroll
        for (int j = 0; j < 4; ++j) {
          float val = acc[mi][nf][j];
          if (SCALED) val *= scale;
          sm += __expf(val - M);
        }
      float s1 = sm + __shfl_xor(sm, 16);
      float Ss = s1 + __shfl_xor(s1, 32);
      if ((lane >> 4) == nf) {
        mb[wr * 256 + ccl[nf]] = M;
        sb[wr * 256 + ccl[nf]] = Ss;
      }
    }
    __syncthreads();
    if (t < 256) {
      float M = fmaxf(fmaxf(mb[t], mb[256 + t]), fmaxf(mb[512 + t], mb[768 + t]));
      float Ss = sb[t] * __expf(mb[t] - M) + sb[256 + t] * __expf(mb[256 + t] - M) +
                 sb[512 + t] * __expf(mb[512 + t] - M) + sb[768 + t] * __expf(mb[768 + t] - M);
      size_t rb = ((size_t)bz * gm + (tile_m >> 8)) * N + tile_n + t;
      red_max[rb] = M;
      red_sum[rb] = Ss;
    }
  }
}

// c[b,k] = 1024 / sum_ch red_sum[b][ch][k]   (x1024 keeps vs in fp8 range)
__global__ __launch_bounds__(256) void combine_c(
    const float* __restrict__ red_sum, float* __restrict__ cvec, int cols, int nch)
{
  const int b = blockIdx.y;
  const int c = blockIdx.x * 256 + threadIdx.x;
  float Z = 0.f;
  for (int ch = 0; ch < nch; ++ch)
    Z += red_sum[((size_t)b * nch + ch) * cols + c];
  cvec[(size_t)b * cols + c] = 1024.f / Z;
}

// vs[b][d][k] = fp8( vpT_fp8[b][d][k] * c[b][k] )   (8 elems/thread)
__global__ __launch_bounds__(256) void scale_v(
    const uint2* __restrict__ vpT, const float* __restrict__ cvec,
    uint2* __restrict__ vs, int S, long DS)
{
  const size_t i8 = (size_t)blockIdx.x * 256 + threadIdx.x;
  const size_t k8 = i8 * 8;
  const int b = (int)(k8 / DS);
  const int kcol = (int)(k8 % S);
  uint2 u = vpT[i8];
  const float* cb = cvec + (size_t)b * S + kcol;
  float f0 = FP8DEC(u.x, 0) * cb[0], f1 = FP8DEC(u.x, 1) * cb[1];
  float f2 = FP8DEC(u.x, 2) * cb[2], f3 = FP8DEC(u.x, 3) * cb[3];
  float f4 = FP8DEC(u.y, 0) * cb[4], f5 = FP8DEC(u.y, 1) * cb[5];
  float f6 = FP8DEC(u.y, 2) * cb[6], f7 = FP8DEC(u.y, 3) * cb[7];
  uint2 o;
  o.x = pk4_fp8(f0, f1, f2, f3);
  o.y = pk4_fp8(f4, f5, f6, f7);
  vs[i8] = o;
}

// combine partials -> M, 1/Z per (b,col). grid: (cols/256, B)
__global__ __launch_bounds__(256) void colsm_combine(
    const float* __restrict__ red_max, const float* __restrict__ red_sum,
    float* __restrict__ Mv, float* __restrict__ Zinv, int cols, int nch)
{
  const int b = blockIdx.y;
  const int c = blockIdx.x * 256 + threadIdx.x;
  float M = -1e30f, Z = 0.f;
  for (int ch = 0; ch < nch; ++ch) {
    size_t o = ((size_t)b * nch + ch) * cols + c;
    float m = red_max[o], s = red_sum[o];
    float nm = fmaxf(M, m);
    Z = Z * __expf(M - nm) + s * __expf(m - nm);
    M = nm;
  }
  Mv[(size_t)b * cols + c] = M;
  Zinv[(size_t)b * cols + c] = 1.f / Z;
}

// final: out1 = softmax(attn over rows), out0 = attn + residual. attn is bf16.
__global__ __launch_bounds__(256) void final_emit(
    const ushort* __restrict__ attnB, const float* __restrict__ q,
    float* __restrict__ out0, float* __restrict__ out1,
    const float* __restrict__ Mv, const float* __restrict__ Zinv,
    int rows, int cols, int rpc)
{
  const int b = blockIdx.y;
  const int ch = blockIdx.z;
  const size_t base = (size_t)b * rows * cols;
  const int c4 = (blockIdx.x * 256 + threadIdx.x) * 4;
  const int r0 = ch * rpc;
  float M[4], Zi[4];
#pragma unroll
  for (int i = 0; i < 4; ++i) {
    M[i] = Mv[(size_t)b * cols + c4 + i];
    Zi[i] = Zinv[(size_t)b * cols + c4 + i];
  }
  for (int r = r0; r < r0 + rpc; ++r) {
    size_t o = base + (size_t)r * cols + c4;
    ushort4 u = *(const ushort4*)(attnB + o);
    float4 qv = *(const float4*)(q + o);
    float a0 = bf2f(u.x), a1 = bf2f(u.y), a2 = bf2f(u.z), a3 = bf2f(u.w);
    float4 wv, s;
    wv.x = __expf(a0 - M[0]) * Zi[0];
    wv.y = __expf(a1 - M[1]) * Zi[1];
    wv.z = __expf(a2 - M[2]) * Zi[2];
    wv.w = __expf(a3 - M[3]) * Zi[3];
    s.x = a0 + qv.x; s.y = a1 + qv.y; s.z = a2 + qv.z; s.w = a3 + qv.w;
    *(float4*)(out1 + o) = wv;
    *(float4*)(out0 + o) = s;
  }
}

extern "C" void kernel_launch(void* const* d_in, const int* in_sizes, int n_in,
                              void* d_out, int out_size, void* d_ws, size_t ws_size,
                              hipStream_t stream) {
  const float* q  = (const float*)d_in[0];
  const float* k  = (const float*)d_in[1];
  const float* v  = (const float*)d_in[2];
  const float* Wq = (const float*)d_in[3];
  const float* bq = (const float*)d_in[4];
  const float* Wk = (const float*)d_in[5];
  const float* bk = (const float*)d_in[6];
  const float* Wv = (const float*)d_in[7];
  const float* bv = (const float*)d_in[8];
  float* out = (float*)d_out;

  const int B = 8, S = 2048, D = 1024;
  const long BS = (long)B * S;
  const long nQKV = BS * D;        // 16.7M elems
  const long nW = (long)D * D;

  // d_out staging (fp8): qb [0,16M), kb [16,32M), vb [32,48M),
  // Wq8/Wk8/Wv8 @48/49/50M; red_s_sum @64M (512KB); c_s @66M (64KB).
  // final_emit overwrites all of d_out at the end.
  unsigned char* qb8 = (unsigned char*)d_out;
  unsigned char* kb8 = qb8 + nQKV;
  unsigned char* vb8 = kb8 + nQKV;
  unsigned char* Wq8 = (unsigned char*)d_out + (48ull << 20);
  unsigned char* Wk8 = (unsigned char*)d_out + (49ull << 20);
  unsigned char* Wv8 = (unsigned char*)d_out + (50ull << 20);
  float* red_s_sum = (float*)((char*)d_out + (64ull << 20));
  float* c_s       = (float*)((char*)d_out + (66ull << 20));

  // ws: qp8 [0,16M), kp8 [16,32M), vpT8 [32,48M), vs8 [48,64M),
  //     expS8 [64,96M), attnB bf16 [96,128M), red_f/Mf/Zf @128M+.
  char* ws = (char*)d_ws;
  unsigned char* qp8   = (unsigned char*)ws;
  unsigned char* kp8   = (unsigned char*)(ws + (16ull << 20));
  unsigned char* vpT8  = (unsigned char*)(ws + (32ull << 20));
  unsigned char* vs8   = (unsigned char*)(ws + (48ull << 20));
  unsigned char* expS8 = (unsigned char*)(ws + (64ull << 20));
  ushort* attnB        = (ushort*)(ws + (96ull << 20));
  float* red_f_max = (float*)(ws + (128ull << 20));
  float* red_f_sum = (float*)(ws + (129ull << 20));
  float* Mf        = (float*)(ws + (130ull << 20));
  float* Zf        = (float*)(ws + (131ull << 20));

  const int SH = 65536;
  (void)hipFuncSetAttribute(reinterpret_cast<const void*>(&gemmF<1,0,0,0,1>),
                            hipFuncAttributeMaxDynamicSharedMemorySize, SH);
  (void)hipFuncSetAttribute(reinterpret_cast<const void*>(&gemmF<2,0,0,0,1>),
                            hipFuncAttributeMaxDynamicSharedMemorySize, SH);
  (void)hipFuncSetAttribute(reinterpret_cast<const void*>(&gemmF<0,1,2,1,1>),
                            hipFuncAttributeMaxDynamicSharedMemorySize, SH);
  (void)hipFuncSetAttribute(reinterpret_cast<const void*>(&gemmF<0,1,1,0,0>),
                            hipFuncAttributeMaxDynamicSharedMemorySize, SH);

  // ---- fp32 -> fp8 conversions: 2 launches (weights; q/k/v) ----
  cvt3_fp8<<<dim3((unsigned)(nW / 4096), 3), 256, 0, stream>>>(
      Wq, Wk, Wv, (uint*)Wq8, (uint*)Wk8, (uint*)Wv8, nW);
  cvt3_fp8<<<dim3((unsigned)(nQKV / 4096), 3), 256, 0, stream>>>(
      q, k, v, (uint*)qb8, (uint*)kb8, (uint*)vb8, nQKV);

  // qp[m][e] = q·Wq + bq (fp8 out)   gm=64, gn=4 -> 256 blocks
  gemmF<1,0,0,0,1><<<dim3(64 * 4), 1024, SH, stream>>>(
      qb8, Wq8, qp8, bq, nullptr, nullptr, D, D, 0, 0, 0, 1.f, 64, 4);
  gemmF<1,0,0,0,1><<<dim3(64 * 4), 1024, SH, stream>>>(
      kb8, Wk8, kp8, bk, nullptr, nullptr, D, D, 0, 0, 0, 1.f, 64, 4);
  // vpT[b][e][s] = Wv·v^T + bv (row bias, fp8 out)   gm=4, gn=8, batch 8
  gemmF<2,0,0,0,1><<<dim3(4 * 8 * B), 1024, SH, stream>>>(
      Wv8, vb8, vpT8, bv, nullptr, nullptr, S, D, 0, (long)S * D, (long)D * S, 1.f, 4, 8);
  // expS = exp(qp·kp^T / 1024) (fp8 out) + fused col-sum partials   gm=8, gn=8, b8
  gemmF<0,1,2,1,1><<<dim3(8 * 8 * B), 1024, SH, stream>>>(
      qp8, kp8, expS8, nullptr, nullptr, red_s_sum,
      S, D, (long)S * D, (long)S * D, (long)S * S, 1.f / 1024.f, 8, 8);

  // c = 1024/colsum;  vs = vpT * c  (fp8)
  combine_c<<<dim3(S / 256, B), 256, 0, stream>>>(red_s_sum, c_s, S, 8);
  scale_v<<<dim3((int)(nQKV / (256 * 8))), 256, 0, stream>>>(
      (const uint2*)vpT8, c_s, (uint2*)vs8, S, (long)D * S);

  // attn = (expS·vs^T)/1024 (bf16 out) + fused final-softmax pass1  gm=8, gn=4, b8
  gemmF<0,1,1,0,0><<<dim3(8 * 4 * B), 1024, SH, stream>>>(
      expS8, vs8, attnB, nullptr, red_f_max, red_f_sum,
      D, S, (long)S * S, (long)D * S, (long)S * D, 1.f / 1024.f, 8, 4);

  colsm_combine<<<dim3(D / 256, B), 256, 0, stream>>>(red_f_max, red_f_sum, Mf, Zf, D, 8);
  final_emit<<<dim3(1, B, 128), 256, 0, stream>>>(attnB, q, out, out + nQKV, Mf, Zf, S, D, 16);

  (void)in_sizes; (void)n_in; (void)out_size; (void)ws_size;
}